// Round 6
// baseline (1868.768 us; speedup 1.0000x reference)
//
#include <hip/hip_runtime.h>
#include <hip/hip_bf16.h>
#include <math.h>

#define NN 1024
#define ND 256
#define NCH 32        // chunks per batch in phase A
#define PSTRIDE 1288  // per-(b,chunk) partial block: 5*256 mu-acc + 5 colsum + pad

typedef __hip_bfloat16 bf;

typedef __attribute__((ext_vector_type(8))) short bf16x8;
typedef __attribute__((ext_vector_type(4))) float f32x4;

// alpha = (1/sqrt(32)) * log2(e); folded into QL so attn uses v_exp (2^x) directly.
#define QL_ALPHA 0.25503486216f
// scale/alpha = ln2
#define WHOLE_LN2 0.6931471805599453f

__device__ __forceinline__ float wave_reduce_sum(float v) {
#pragma unroll
    for (int off = 32; off > 0; off >>= 1) v += __shfl_down(v, off, 64);
    return v;
}
__device__ __forceinline__ float wave_allreduce_sum(float v) {
#pragma unroll
    for (int off = 1; off < 64; off <<= 1) v += __shfl_xor(v, off, 64);
    return v;
}

__global__ void zero_k(float* __restrict__ out, unsigned int* __restrict__ sync) {
    int i = blockIdx.x * 1024 + threadIdx.x;
    out[(size_t)i * 8] = 0.f;
    if (blockIdx.x == 0 && threadIdx.x < 176) sync[threadIdx.x] = 0u;
}

// ---------------- split-bf16 MFMA GEMM: QL = alpha*(query@W0^T+b0) ; KL = key@W1^T+b1 ----------------
__global__ __launch_bounds__(256) void gemm2_k(
    const float* __restrict__ Aq, const float* __restrict__ Ak,
    const float* __restrict__ W0, const float* __restrict__ b0v,
    const float* __restrict__ W1, const float* __restrict__ b1v,
    bf* __restrict__ QL, bf* __restrict__ KL)
{
    const float* A; const float* Bw; const float* bias; bf* C; float alpha;
    if (blockIdx.z == 0) { A = Aq; Bw = W0; bias = b0v; C = QL; alpha = QL_ALPHA; }
    else                 { A = Ak; Bw = W1; bias = b1v; C = KL; alpha = 1.0f; }
    __shared__ short Ahi[4 * 64 * 8],  Alo[4 * 64 * 8];
    __shared__ short Bhi[16 * 64 * 8], Blo[16 * 64 * 8];
    const int t = threadIdx.x;
    const int wave = t >> 6, lane = t & 63;
    const int m0 = blockIdx.x * 64;

    f32x4 acc[4][4];
#pragma unroll
    for (int m = 0; m < 4; m++)
#pragma unroll
        for (int n = 0; n < 4; n++)
#pragma unroll
            for (int r = 0; r < 4; r++) acc[m][n][r] = 0.f;

    for (int k0 = 0; k0 < 256; k0 += 32) {
        __syncthreads();
        {
            int fm = t >> 6, ls = t & 63;
            const float* src = A + (size_t)(m0 + fm * 16 + (ls & 15)) * 256 + k0 + ((ls >> 4) * 8);
            float4 x = *(const float4*)src;
            float4 y = *(const float4*)(src + 4);
            float v[8] = {x.x, x.y, x.z, x.w, y.x, y.y, y.z, y.w};
            short h[8], l8[8];
#pragma unroll
            for (int j = 0; j < 8; j++) {
                bf hb = __float2bfloat16(v[j]);
                float hf = __bfloat162float(hb);
                bf lb = __float2bfloat16(v[j] - hf);
                h[j] = *(short*)&hb; l8[j] = *(short*)&lb;
            }
            *(bf16x8*)&Ahi[t * 8] = *(bf16x8*)h;
            *(bf16x8*)&Alo[t * 8] = *(bf16x8*)l8;
        }
#pragma unroll
        for (int i = 0; i < 4; i++) {
            int idx = t + i * 256;
            int nf = idx >> 6, ls = idx & 63;
            const float* src = Bw + (size_t)(nf * 16 + (ls & 15)) * 256 + k0 + ((ls >> 4) * 8);
            float4 x = *(const float4*)src;
            float4 y = *(const float4*)(src + 4);
            float v[8] = {x.x, x.y, x.z, x.w, y.x, y.y, y.z, y.w};
            short h[8], l8[8];
#pragma unroll
            for (int j = 0; j < 8; j++) {
                bf hb = __float2bfloat16(v[j]);
                float hf = __bfloat162float(hb);
                bf lb = __float2bfloat16(v[j] - hf);
                h[j] = *(short*)&hb; l8[j] = *(short*)&lb;
            }
            *(bf16x8*)&Bhi[idx * 8] = *(bf16x8*)h;
            *(bf16x8*)&Blo[idx * 8] = *(bf16x8*)l8;
        }
        __syncthreads();
        bf16x8 ah[4], al[4], bh[4], bl[4];
#pragma unroll
        for (int m = 0; m < 4; m++) {
            ah[m] = *(const bf16x8*)&Ahi[(m * 64 + lane) * 8];
            al[m] = *(const bf16x8*)&Alo[(m * 64 + lane) * 8];
        }
#pragma unroll
        for (int n = 0; n < 4; n++) {
            int nf = wave * 4 + n;
            bh[n] = *(const bf16x8*)&Bhi[(nf * 64 + lane) * 8];
            bl[n] = *(const bf16x8*)&Blo[(nf * 64 + lane) * 8];
        }
#pragma unroll
        for (int m = 0; m < 4; m++)
#pragma unroll
            for (int n = 0; n < 4; n++) {
                acc[m][n] = __builtin_amdgcn_mfma_f32_16x16x32_bf16(ah[m], bh[n], acc[m][n], 0, 0, 0);
                acc[m][n] = __builtin_amdgcn_mfma_f32_16x16x32_bf16(ah[m], bl[n], acc[m][n], 0, 0, 0);
                acc[m][n] = __builtin_amdgcn_mfma_f32_16x16x32_bf16(al[m], bh[n], acc[m][n], 0, 0, 0);
            }
    }
#pragma unroll
    for (int n = 0; n < 4; n++) {
        int col = (wave * 4 + n) * 16 + (lane & 15);
        float bv = bias[col];
#pragma unroll
        for (int m = 0; m < 4; m++) {
            int row = m0 + m * 16 + (lane >> 4) * 4;
#pragma unroll
            for (int r = 0; r < 4; r++) {
                bf hv = __float2bfloat16((acc[m][n][r] + bv) * alpha);
                C[(size_t)(row + r) * 256 + col] = hv;
            }
        }
    }
}

// ---------------- KG[b][h][c] = sum_l KL[b,l,h*32+c] * value[b,l] ----------------
__global__ __launch_bounds__(256) void kg_k(
    const bf* __restrict__ KL, const float* __restrict__ value, float* __restrict__ KG)
{
    const int bh = blockIdx.x, b = bh >> 3, h = bh & 7;
    const int t = threadIdx.x;
    const int c = t & 31, rg = t >> 5;   // 8 row-groups of 128 rows
    float acc = 0.f;
    const bf* kp = KL + (size_t)b * NN * ND + h * 32 + c;
    const float* vp = value + (size_t)b * NN;
#pragma unroll 8
    for (int r = rg * 128; r < rg * 128 + 128; r++)
        acc += __bfloat162float(kp[(size_t)r * ND]) * vp[r];
    __shared__ float kgs[8][33];
    kgs[rg][c] = acc;
    __syncthreads();
    if (t < 32) {
        float s = 0.f;
#pragma unroll
        for (int g = 0; g < 8; g++) s += kgs[g][t];
        KG[(size_t)bh * 32 + t] = s;
    }
}

// ---------------- MFMA flash attention: 64 q-rows/wave, v_exp inner, KG-based whole ----------------
__global__ __launch_bounds__(256) void attn5_k(
    const bf* __restrict__ QL, const bf* __restrict__ KL,
    const float* __restrict__ value, const float* __restrict__ lamda,
    const float* __restrict__ KG, float* __restrict__ out)
{
    const int bh = blockIdx.x; const int b = bh >> 3, h = bh & 7;
    const int t = threadIdx.x;
    const int wave = t >> 6, lane = t & 63;
    const int q0 = blockIdx.y * 256 + wave * 64;

    __shared__ bf Kf[128 * 32];   // 512 fragments * 8 bf16, fragment order
    __shared__ float vv[128];

    bf16x8 qf[4];
    {
        const bf* qbase = QL + ((size_t)b * NN) * ND + h * 32 + (lane >> 4) * 8;
#pragma unroll
        for (int m = 0; m < 4; m++)
            qf[m] = *(const bf16x8*)(qbase + (size_t)(q0 + m * 16 + (lane & 15)) * ND);
    }
    f32x4 lsum[4], vacc[4];
#pragma unroll
    for (int m = 0; m < 4; m++)
#pragma unroll
        for (int r = 0; r < 4; r++) { lsum[m][r] = 0.f; vacc[m][r] = 0.f; }

    const bf* kbase = KL + ((size_t)b * NN) * ND + h * 32;
    for (int kt = 0; kt < 8; kt++) {
        const int k0 = kt * 128;
        __syncthreads();
#pragma unroll
        for (int i = 0; i < 2; i++) {
            int f = t + i * 256;
            int row = ((f >> 6) << 4) + (f & 15);
            int chunk = (f >> 4) & 3;
            *(bf16x8*)&Kf[f * 8] = *(const bf16x8*)(kbase + (size_t)(k0 + row) * ND + chunk * 8);
        }
        if (t < 128) vv[t] = value[(size_t)b * NN + k0 + t];
        __syncthreads();
#pragma unroll
        for (int s = 0; s < 8; s++) {
            bf16x8 bfr = *(const bf16x8*)&Kf[(s * 64 + lane) * 8];
            float vcol = vv[s * 16 + (lane & 15)];
#pragma unroll
            for (int m = 0; m < 4; m++) {
                f32x4 acc = {0.f, 0.f, 0.f, 0.f};
                acc = __builtin_amdgcn_mfma_f32_16x16x32_bf16(qf[m], bfr, acc, 0, 0, 0);
#pragma unroll
                for (int r = 0; r < 4; r++) {
                    float p;
                    asm("v_exp_f32 %0, %1\n\ts_nop 0" : "=v"(p) : "v"(acc[r]));
                    lsum[m][r] += p;
                    vacc[m][r] += p * vcol;
                }
            }
        }
    }
    // epilogue: whole from q.KG (linear in k: sum_l (q.k_l) v_l = q . KG)
    float kgf[8];
#pragma unroll
    for (int j = 0; j < 8; j++) kgf[j] = KG[(size_t)bh * 32 + (lane >> 4) * 8 + j];
    const float lam = lamda[0];
#pragma unroll
    for (int m = 0; m < 4; m++) {
        float dot = 0.f;
#pragma unroll
        for (int j = 0; j < 8; j++) {
            float qj = __uint_as_float(((unsigned int)(unsigned short)qf[m][j]) << 16);
            dot += qj * kgf[j];
        }
        dot += __shfl_xor(dot, 16, 64);
        dot += __shfl_xor(dot, 32, 64);   // lane l now holds full dot for row (l&15)
#pragma unroll
        for (int r = 0; r < 4; r++) {
            float ls = lsum[m][r], va = vacc[m][r];
#pragma unroll
            for (int off = 1; off < 16; off <<= 1) {
                ls += __shfl_xor(ls, off, 64);
                va += __shfl_xor(va, off, 64);
            }
            float dw = __shfl(dot, (lane >> 4) * 4 + r, 64);
            if ((lane & 15) == 0) {
                int q = q0 + m * 16 + (lane >> 4) * 4 + r;
                float part = va / ls;
                float whole = fmaxf(dw * (WHOLE_LN2 / 1024.0f), 0.f);
                float f = ((1.f - lam) * part + lam * whole) * 0.125f;
                atomicAdd(&out[((size_t)b * NN + q) * 8], f);
            }
        }
    }
}

// ---------------- pmmsA_k: ALL 10 phase-A stages + phase B in ONE launch ----------------
// grid (NCH, 16) x 256, cooperative (co-residency guarantee only; NO grid.sync).
// Per-batch sync: each block deposits partials, tickets cnt[stage][b]; the last
// block reduces partials -> muG[b], releases flag[b]=stage+1; others spin on flag.
__global__ __launch_bounds__(256) void pmmsA_k(
    const float* __restrict__ query, const float* __restrict__ mu0a,
    const float* __restrict__ mu0b,
    float* __restrict__ PP, float* __restrict__ muG,
    float* __restrict__ m1w, float* __restrict__ mu2w,
    unsigned int* __restrict__ cnt, unsigned int* __restrict__ flag)
{
    __shared__ float muT[5 * 256];  // [k][c]
    __shared__ float z_s[32][8];    // [n_local][k]
    __shared__ float red[32];
    __shared__ unsigned int lastLds;
    const int chunk = blockIdx.x, b = blockIdx.y;
    const int t = threadIdx.x;
    const int wave = t >> 6, lane = t & 63;
    const int n_local = t >> 3, part = t & 7;
    float* pb = PP + ((size_t)(b * NCH + chunk)) * PSTRIDE;

    for (int st = 0; st < 10; st++) {
        // ---- obtain mu for this stage ----
        if (st == 0) {
            for (int idx = t; idx < 1280; idx += 256)
                muT[idx] = mu0a[(idx & 255) * 5 + (idx >> 8)];
        } else {
            if (t == 0) {
                while (__hip_atomic_load(&flag[b], __ATOMIC_ACQUIRE, __HIP_MEMORY_SCOPE_AGENT) < (unsigned)st)
                    __builtin_amdgcn_s_sleep(8);
            }
            __syncthreads();
            for (int idx = t; idx < 1280; idx += 256)
                muT[idx] = muG[(size_t)b * 1280 + idx];
        }
        __syncthreads();

        // ---- z-pass: 32 rows, 8 lanes/row ----
        {
            const float* qrow = query + ((size_t)b * NN + chunk * 32 + n_local) * ND + part * 32;
            float lg[5] = {0,0,0,0,0};
#pragma unroll
            for (int c4 = 0; c4 < 32; c4 += 4) {
                float4 qv = *(const float4*)&qrow[c4];
#pragma unroll
                for (int k = 0; k < 5; k++) {
                    float4 mv = *(const float4*)&muT[k * 256 + part * 32 + c4];
                    lg[k] += qv.x*mv.x + qv.y*mv.y + qv.z*mv.z + qv.w*mv.w;
                }
            }
#pragma unroll
            for (int k = 0; k < 5; k++) {
                lg[k] += __shfl_xor(lg[k], 1, 64);
                lg[k] += __shfl_xor(lg[k], 2, 64);
                lg[k] += __shfl_xor(lg[k], 4, 64);
            }
            float mx = lg[0];
#pragma unroll
            for (int k = 1; k < 5; k++) mx = fmaxf(mx, lg[k]);
            float e[5], ssum = 0.f;
#pragma unroll
            for (int k = 0; k < 5; k++) { e[k] = expf(20.0f * (lg[k] - mx)); ssum += e[k]; }
            float is = 1.0f / ssum;
            if (part == 0) {
#pragma unroll
                for (int k = 0; k < 5; k++) z_s[n_local][k] = e[k] * is;
            }
        }
        __syncthreads();

        // ---- partial mu accumulation: thread owns c = t ----
        {
            float pa[5] = {0,0,0,0,0};
            const float* qcol = query + ((size_t)b * NN + chunk * 32) * ND + t;
#pragma unroll 4
            for (int nl = 0; nl < 32; nl++) {
                float qv = qcol[(size_t)nl * ND];
                float4 z4 = *(const float4*)&z_s[nl][0];
                float z4v = z_s[nl][4];
                pa[0] += qv * z4.x; pa[1] += qv * z4.y; pa[2] += qv * z4.z;
                pa[3] += qv * z4.w; pa[4] += qv * z4v;
            }
#pragma unroll
            for (int k = 0; k < 5; k++) pb[k * 256 + t] = pa[k];
            if (t < 5) {
                float s2 = 0.f;
                for (int nl = 0; nl < 32; nl++) s2 += z_s[nl][t];
                pb[1280 + t] = s2;
            }
        }
        __threadfence();
        __syncthreads();
        if (t == 0) {
            unsigned int tk = __hip_atomic_fetch_add(&cnt[st * 16 + b], 1u,
                                                     __ATOMIC_ACQ_REL, __HIP_MEMORY_SCOPE_AGENT);
            lastLds = (tk == (unsigned)(NCH - 1)) ? 1u : 0u;
        }
        __syncthreads();
        if (lastLds) {
            // last block of this batch: reduce all chunks' partials -> mu
            float mr[5] = {0,0,0,0,0};
            float cs[5] = {0,0,0,0,0};
            __threadfence();
#pragma unroll 2
            for (int ch = 0; ch < NCH; ch++) {
                const float* p2 = PP + ((size_t)(b * NCH + ch)) * PSTRIDE;
#pragma unroll
                for (int k = 0; k < 5; k++) mr[k] += p2[k * 256 + t];
#pragma unroll
                for (int k = 0; k < 5; k++) cs[k] += p2[1280 + k];
            }
#pragma unroll
            for (int k = 0; k < 5; k++) mr[k] *= 1.0f / (1e-6f + cs[k]);
#pragma unroll
            for (int k = 0; k < 5; k++) {
                float s2 = wave_reduce_sum(mr[k] * mr[k]);
                if (lane == 0) red[wave * 5 + k] = s2;
            }
            __syncthreads();
            if (t < 5) red[20 + t] = 1.0f / (1e-6f + sqrtf(red[t] + red[5 + t] + red[10 + t] + red[15 + t]));
            __syncthreads();
            if (st < 9) {
#pragma unroll
                for (int k = 0; k < 5; k++)
                    muG[(size_t)b * 1280 + k * 256 + t] = mr[k] * red[20 + k];
                __threadfence();
                if (t == 0)
                    __hip_atomic_store(&flag[b], (unsigned)(st + 1), __ATOMIC_RELEASE, __HIP_MEMORY_SCOPE_AGENT);
            } else {
                // m1 = final mu; write m1w + keep in LDS for phase B
#pragma unroll
                for (int k = 0; k < 5; k++) {
                    float v = mr[k] * red[20 + k];
                    m1w[(size_t)b * 1280 + k * 256 + t] = v;
                    muT[k * 256 + t] = v;
                }
                __syncthreads();
                // ---- phase B on wave 0 ----
                if (t < 64) {
                    const int ln = t;
                    float nd[5][4];
#pragma unroll
                    for (int n = 0; n < 5; n++)
#pragma unroll
                        for (int j = 0; j < 4; j++) nd[n][j] = muT[n * 256 + ln + 64 * j];
                    float mu[2][4];
#pragma unroll
                    for (int k = 0; k < 2; k++)
#pragma unroll
                        for (int j = 0; j < 4; j++) mu[k][j] = mu0b[(ln + 64 * j) * 2 + k];
                    for (int sb = 0; sb < 10; sb++) {
                        float z[5][2];
                        float colsum0 = 0.f, colsum1 = 0.f;
#pragma unroll
                        for (int n = 0; n < 5; n++) {
                            float l0 = 0.f, l1 = 0.f;
#pragma unroll
                            for (int j = 0; j < 4; j++) { l0 += nd[n][j] * mu[0][j]; l1 += nd[n][j] * mu[1][j]; }
                            l0 = wave_allreduce_sum(l0);
                            l1 = wave_allreduce_sum(l1);
                            float a0 = 20.0f * l0, a1 = 20.0f * l1;
                            float mxv = fmaxf(a0, a1);
                            float e0 = expf(a0 - mxv), e1 = expf(a1 - mxv);
                            float inv = 1.0f / (e0 + e1);
                            z[n][0] = e0 * inv; z[n][1] = e1 * inv;
                            colsum0 += z[n][0]; colsum1 += z[n][1];
                        }
                        float i0 = 1.0f / (1e-6f + colsum0), i1 = 1.0f / (1e-6f + colsum1);
#pragma unroll
                        for (int k = 0; k < 2; k++) {
                            float iv = k ? i1 : i0;
                            float sq = 0.f;
                            float nm[4];
#pragma unroll
                            for (int j = 0; j < 4; j++) {
                                float v = 0.f;
#pragma unroll
                                for (int n = 0; n < 5; n++) v += nd[n][j] * z[n][k];
                                v *= iv;
                                nm[j] = v; sq += v * v;
                            }
                            float s2 = wave_allreduce_sum(sq);
                            float nr = 1.0f / (1e-6f + sqrtf(s2));
#pragma unroll
                            for (int j = 0; j < 4; j++) mu[k][j] = nm[j] * nr;
                        }
                    }
#pragma unroll
                    for (int k = 0; k < 2; k++)
#pragma unroll
                        for (int j = 0; j < 4; j++)
                            mu2w[((size_t)b * 2 + k) * 256 + ln + 64 * j] = mu[k][j];
                }
            }
        }
    }
}

// ---------------- P1 = softmax(q.m1), P2 = softmax(q.mu2) ----------------
__global__ __launch_bounds__(256) void pmap_k(
    const float* __restrict__ query, const float* __restrict__ m1_ws,
    const float* __restrict__ mu2_ws, float* __restrict__ P1, float* __restrict__ P2)
{
    __shared__ float ms[7 * 256];
    int b = blockIdx.y;
    int t = threadIdx.x;
    int n = blockIdx.x * 256 + t;
    for (int idx = t; idx < 1280; idx += 256) ms[idx] = m1_ws[(size_t)b * 1280 + idx];
    for (int idx = t; idx < 512; idx += 256) ms[1280 + idx] = mu2_ws[(size_t)b * 512 + idx];
    __syncthreads();
    const float* qrow = query + ((size_t)b * NN + n) * ND;
    float lg[7] = {0,0,0,0,0,0,0};
    for (int c4 = 0; c4 < 256; c4 += 4) {
        float4 qv = *(const float4*)&qrow[c4];
#pragma unroll
        for (int k = 0; k < 7; k++) {
            float4 mv = *(const float4*)&ms[k * 256 + c4];
            lg[k] += qv.x*mv.x + qv.y*mv.y + qv.z*mv.z + qv.w*mv.w;
        }
    }
    float mx = lg[0];
#pragma unroll
    for (int k = 1; k < 5; k++) mx = fmaxf(mx, lg[k]);
    float e[5], ssum = 0.f;
#pragma unroll
    for (int k = 0; k < 5; k++) { e[k] = expf(lg[k] - mx); ssum += e[k]; }
    float is = 1.0f / ssum;
#pragma unroll
    for (int k = 0; k < 5; k++) P1[((size_t)b * 5 + k) * NN + n] = e[k] * is;
    float mx2 = fmaxf(lg[5], lg[6]);
    float e0 = expf(lg[5] - mx2), e1 = expf(lg[6] - mx2);
    float inv = 1.0f / (e0 + e1);
    P2[((size_t)b * 2 + 0) * NN + n] = e0 * inv;
    P2[((size_t)b * 2 + 1) * NN + n] = e1 * inv;
}

// ---------------- node_weight conv: one (b, ch) per block, 3 barriers total ----------------
__global__ __launch_bounds__(1024) void nwconv_k(
    const float* __restrict__ P1, const float* __restrict__ P2,
    const float* __restrict__ w1a, const float* __restrict__ b1a,
    const float* __restrict__ ga,  const float* __restrict__ bea,
    const float* __restrict__ w2a, const float* __restrict__ b2a,
    const float* __restrict__ w1b, const float* __restrict__ b1b,
    const float* __restrict__ gb,  const float* __restrict__ beb,
    const float* __restrict__ w2b, const float* __restrict__ b2b,
    float* __restrict__ out)
{
    __shared__ float img[34 * 34];
    __shared__ float mid[16][34 * 34];
    __shared__ float w1s[144], w2s[144], bs[16], gs[16], bes[16], b2s[1];
    int ch = blockIdx.x, b = blockIdx.y;
    int t = threadIdx.x;
    int i = t >> 5, j = t & 31;
    const float* xsrc = (ch < 5) ? &P1[((size_t)b * 5 + ch) * NN]
                                 : &P2[((size_t)b * 2 + (ch - 5)) * NN];
    if (t < 144) { w1s[t] = (ch < 5 ? w1a : w1b)[t]; w2s[t] = (ch < 5 ? w2a : w2b)[t]; }
    if (t >= 256 && t < 272) {
        int y = t - 256;
        bs[y] = (ch < 5 ? b1a : b1b)[y];
        gs[y] = (ch < 5 ? ga : gb)[y];
        bes[y] = (ch < 5 ? bea : beb)[y];
    }
    if (t == 512) b2s[0] = (ch < 5 ? b2a : b2b)[0];
    for (int idx = t; idx < 1156; idx += 1024) img[idx] = 0.f;
    for (int idx = t; idx < 16 * 1156; idx += 1024) ((float*)mid)[idx] = 0.f;
    __syncthreads();
    float xv = xsrc[t];
    img[(i + 1) * 34 + (j + 1)] = xv;
    __syncthreads();
    float r[9];
#pragma unroll
    for (int dy = 0; dy < 3; dy++)
#pragma unroll
        for (int dx = 0; dx < 3; dx++)
            r[dy * 3 + dx] = img[(i + dy) * 34 + (j + dx)];
    const float bninv = rsqrtf(1.0f + 1e-5f);
#pragma unroll
    for (int oc = 0; oc < 16; oc++) {
        float a = 0.f;
#pragma unroll
        for (int q2 = 0; q2 < 9; q2++) a += w1s[oc * 9 + q2] * r[q2];
        a += bs[oc];
        a = gs[oc] * (a * bninv) + bes[oc];
        a = fmaxf(a, 0.f);
        mid[oc][(i + 1) * 34 + (j + 1)] = a;
    }
    __syncthreads();
    float acc2 = b2s[0];
#pragma unroll
    for (int oc = 0; oc < 16; oc++)
#pragma unroll
        for (int dy = 0; dy < 3; dy++)
#pragma unroll
            for (int dx = 0; dx < 3; dx++)
                acc2 += w2s[oc * 9 + dy * 3 + dx] * mid[oc][(i + dy) * 34 + (j + dx)];
    float sig = 1.0f / (1.0f + expf(-acc2));
    out[((size_t)(b * NN + t)) * 8 + 1 + ch] = xv * sig;
}

extern "C" void kernel_launch(void* const* d_in, const int* in_sizes, int n_in,
                              void* d_out, int out_size, void* d_ws, size_t ws_size,
                              hipStream_t stream) {
    const float* query = (const float*)d_in[0];
    const float* key   = (const float*)d_in[1];
    const float* value = (const float*)d_in[2];
    const float* lamda = (const float*)d_in[3];
    const float* W0 = (const float*)d_in[4];
    const float* b0 = (const float*)d_in[5];
    const float* W1 = (const float*)d_in[6];
    const float* b1 = (const float*)d_in[7];
    const float* mu_a = (const float*)d_in[8];
    const float* mu_b = (const float*)d_in[9];
    const float* nw1_w1 = (const float*)d_in[10];
    const float* nw1_b1 = (const float*)d_in[11];
    const float* nw1_g  = (const float*)d_in[12];
    const float* nw1_be = (const float*)d_in[13];
    const float* nw1_w2 = (const float*)d_in[14];
    const float* nw1_b2 = (const float*)d_in[15];
    const float* nw2_w1 = (const float*)d_in[16];
    const float* nw2_b1 = (const float*)d_in[17];
    const float* nw2_g  = (const float*)d_in[18];
    const float* nw2_be = (const float*)d_in[19];
    const float* nw2_w2 = (const float*)d_in[20];
    const float* nw2_b2 = (const float*)d_in[21];
    float* out = (float*)d_out;

    // ws: QLb [0,8MB) + KLb [8,16MB) as bf16 (attention path).
    bf* QLb = (bf*)d_ws;
    bf* KLb = (bf*)((char*)d_ws + ((size_t)8 << 20));
    // PMMS scratch (~3.3 MB) OVERLAYS the QLb region (attn completes first on stream).
    float* PP   = (float*)d_ws;
    float* m1w  = PP  + (size_t)16 * NCH * PSTRIDE;
    float* mu2w = m1w + (size_t)16 * 1280;
    float* P1w  = mu2w + (size_t)16 * 512;
    float* P2w  = P1w + (size_t)16 * 5 * 1024;
    float* muG  = P2w + (size_t)16 * 2 * 1024;
    // Outside the 16MB QL/KL span: KG (16KB) + sync (176 uints) — NOT overlaid.
    float* KGw = (float*)((char*)d_ws + ((size_t)16 << 20));
    unsigned int* syncb = (unsigned int*)((char*)d_ws + ((size_t)16 << 20) + (16 << 10));
    unsigned int* cntb = syncb;           // [160]
    unsigned int* flagb = syncb + 160;    // [16]

    zero_k<<<16, 1024, 0, stream>>>(out, syncb);
    gemm2_k<<<dim3(256, 1, 2), 256, 0, stream>>>(query, key, W0, b0, W1, b1, QLb, KLb);
    kg_k<<<128, 256, 0, stream>>>(KLb, value, KGw);
    attn5_k<<<dim3(128, 4), 256, 0, stream>>>(QLb, KLb, value, lamda, KGw, out);

    {
        void* args[] = {
            (void*)&query, (void*)&mu_a, (void*)&mu_b,
            (void*)&PP, (void*)&muG, (void*)&m1w, (void*)&mu2w,
            (void*)&cntb, (void*)&flagb
        };
        hipLaunchCooperativeKernel((void*)pmmsA_k, dim3(NCH, 16), dim3(256),
                                   args, 0, stream);
    }

    pmap_k<<<dim3(4, 16), 256, 0, stream>>>(query, m1w, mu2w, P1w, P2w);
    nwconv_k<<<dim3(7, 16), 1024, 0, stream>>>(P1w, P2w,
                                    nw1_w1, nw1_b1, nw1_g, nw1_be, nw1_w2, nw1_b2,
                                    nw2_w1, nw2_b1, nw2_g, nw2_be, nw2_w2, nw2_b2, out);
}

// Round 7
// 357.698 us; speedup vs baseline: 5.2244x; 5.2244x over previous
//
#include <hip/hip_runtime.h>
#include <hip/hip_bf16.h>
#include <math.h>

#define NN 1024
#define ND 256
#define NCH 8         // chunks per batch in phase A (128 rows per chunk)
#define PSTRIDE 1288  // per-(b,chunk) partial block: 5*256 mu-acc + 5 colsum + pad

typedef __hip_bfloat16 bf;

typedef __attribute__((ext_vector_type(8))) short bf16x8;
typedef __attribute__((ext_vector_type(4))) float f32x4;

// alpha = (1/sqrt(32)) * log2(e); folded into QL so attn uses v_exp (2^x) directly.
#define QL_ALPHA 0.25503486216f
// scale/alpha = ln2
#define WHOLE_LN2 0.6931471805599453f

__device__ __forceinline__ float wave_reduce_sum(float v) {
#pragma unroll
    for (int off = 32; off > 0; off >>= 1) v += __shfl_down(v, off, 64);
    return v;
}
__device__ __forceinline__ float wave_allreduce_sum(float v) {
#pragma unroll
    for (int off = 1; off < 64; off <<= 1) v += __shfl_xor(v, off, 64);
    return v;
}

__global__ void zero_k(float* __restrict__ out) {
    int i = blockIdx.x * 1024 + threadIdx.x;
    out[(size_t)i * 8] = 0.f;
}

// ---------------- split-bf16 MFMA GEMM: QL = alpha*(query@W0^T+b0) ; KL = key@W1^T+b1 ----------------
__global__ __launch_bounds__(256) void gemm2_k(
    const float* __restrict__ Aq, const float* __restrict__ Ak,
    const float* __restrict__ W0, const float* __restrict__ b0v,
    const float* __restrict__ W1, const float* __restrict__ b1v,
    bf* __restrict__ QL, bf* __restrict__ KL)
{
    const float* A; const float* Bw; const float* bias; bf* C; float alpha;
    if (blockIdx.z == 0) { A = Aq; Bw = W0; bias = b0v; C = QL; alpha = QL_ALPHA; }
    else                 { A = Ak; Bw = W1; bias = b1v; C = KL; alpha = 1.0f; }
    __shared__ short Ahi[4 * 64 * 8],  Alo[4 * 64 * 8];
    __shared__ short Bhi[16 * 64 * 8], Blo[16 * 64 * 8];
    const int t = threadIdx.x;
    const int wave = t >> 6, lane = t & 63;
    const int m0 = blockIdx.x * 64;

    f32x4 acc[4][4];
#pragma unroll
    for (int m = 0; m < 4; m++)
#pragma unroll
        for (int n = 0; n < 4; n++)
#pragma unroll
            for (int r = 0; r < 4; r++) acc[m][n][r] = 0.f;

    for (int k0 = 0; k0 < 256; k0 += 32) {
        __syncthreads();
        {
            int fm = t >> 6, ls = t & 63;
            const float* src = A + (size_t)(m0 + fm * 16 + (ls & 15)) * 256 + k0 + ((ls >> 4) * 8);
            float4 x = *(const float4*)src;
            float4 y = *(const float4*)(src + 4);
            float v[8] = {x.x, x.y, x.z, x.w, y.x, y.y, y.z, y.w};
            short h[8], l8[8];
#pragma unroll
            for (int j = 0; j < 8; j++) {
                bf hb = __float2bfloat16(v[j]);
                float hf = __bfloat162float(hb);
                bf lb = __float2bfloat16(v[j] - hf);
                h[j] = *(short*)&hb; l8[j] = *(short*)&lb;
            }
            *(bf16x8*)&Ahi[t * 8] = *(bf16x8*)h;
            *(bf16x8*)&Alo[t * 8] = *(bf16x8*)l8;
        }
#pragma unroll
        for (int i = 0; i < 4; i++) {
            int idx = t + i * 256;
            int nf = idx >> 6, ls = idx & 63;
            const float* src = Bw + (size_t)(nf * 16 + (ls & 15)) * 256 + k0 + ((ls >> 4) * 8);
            float4 x = *(const float4*)src;
            float4 y = *(const float4*)(src + 4);
            float v[8] = {x.x, x.y, x.z, x.w, y.x, y.y, y.z, y.w};
            short h[8], l8[8];
#pragma unroll
            for (int j = 0; j < 8; j++) {
                bf hb = __float2bfloat16(v[j]);
                float hf = __bfloat162float(hb);
                bf lb = __float2bfloat16(v[j] - hf);
                h[j] = *(short*)&hb; l8[j] = *(short*)&lb;
            }
            *(bf16x8*)&Bhi[idx * 8] = *(bf16x8*)h;
            *(bf16x8*)&Blo[idx * 8] = *(bf16x8*)l8;
        }
        __syncthreads();
        bf16x8 ah[4], al[4], bh[4], bl[4];
#pragma unroll
        for (int m = 0; m < 4; m++) {
            ah[m] = *(const bf16x8*)&Ahi[(m * 64 + lane) * 8];
            al[m] = *(const bf16x8*)&Alo[(m * 64 + lane) * 8];
        }
#pragma unroll
        for (int n = 0; n < 4; n++) {
            int nf = wave * 4 + n;
            bh[n] = *(const bf16x8*)&Bhi[(nf * 64 + lane) * 8];
            bl[n] = *(const bf16x8*)&Blo[(nf * 64 + lane) * 8];
        }
#pragma unroll
        for (int m = 0; m < 4; m++)
#pragma unroll
            for (int n = 0; n < 4; n++) {
                acc[m][n] = __builtin_amdgcn_mfma_f32_16x16x32_bf16(ah[m], bh[n], acc[m][n], 0, 0, 0);
                acc[m][n] = __builtin_amdgcn_mfma_f32_16x16x32_bf16(ah[m], bl[n], acc[m][n], 0, 0, 0);
                acc[m][n] = __builtin_amdgcn_mfma_f32_16x16x32_bf16(al[m], bh[n], acc[m][n], 0, 0, 0);
            }
    }
#pragma unroll
    for (int n = 0; n < 4; n++) {
        int col = (wave * 4 + n) * 16 + (lane & 15);
        float bv = bias[col];
#pragma unroll
        for (int m = 0; m < 4; m++) {
            int row = m0 + m * 16 + (lane >> 4) * 4;
#pragma unroll
            for (int r = 0; r < 4; r++) {
                bf hv = __float2bfloat16((acc[m][n][r] + bv) * alpha);
                C[(size_t)(row + r) * 256 + col] = hv;
            }
        }
    }
}

// ---------------- KG[b][h][c] = sum_l KL[b,l,h*32+c] * value[b,l] ----------------
__global__ __launch_bounds__(256) void kg_k(
    const bf* __restrict__ KL, const float* __restrict__ value, float* __restrict__ KG)
{
    const int bh = blockIdx.x, b = bh >> 3, h = bh & 7;
    const int t = threadIdx.x;
    const int c = t & 31, rg = t >> 5;   // 8 row-groups of 128 rows
    float acc = 0.f;
    const bf* kp = KL + (size_t)b * NN * ND + h * 32 + c;
    const float* vp = value + (size_t)b * NN;
#pragma unroll 8
    for (int r = rg * 128; r < rg * 128 + 128; r++)
        acc += __bfloat162float(kp[(size_t)r * ND]) * vp[r];
    __shared__ float kgs[8][33];
    kgs[rg][c] = acc;
    __syncthreads();
    if (t < 32) {
        float s = 0.f;
#pragma unroll
        for (int g = 0; g < 8; g++) s += kgs[g][t];
        KG[(size_t)bh * 32 + t] = s;
    }
}

// ---------------- MFMA flash attention: 64 q-rows/wave, v_exp inner, KG-based whole ----------------
__global__ __launch_bounds__(256) void attn5_k(
    const bf* __restrict__ QL, const bf* __restrict__ KL,
    const float* __restrict__ value, const float* __restrict__ lamda,
    const float* __restrict__ KG, float* __restrict__ out)
{
    const int bh = blockIdx.x; const int b = bh >> 3, h = bh & 7;
    const int t = threadIdx.x;
    const int wave = t >> 6, lane = t & 63;
    const int q0 = blockIdx.y * 256 + wave * 64;

    __shared__ bf Kf[128 * 32];   // 512 fragments * 8 bf16, fragment order
    __shared__ float vv[128];

    bf16x8 qf[4];
    {
        const bf* qbase = QL + ((size_t)b * NN) * ND + h * 32 + (lane >> 4) * 8;
#pragma unroll
        for (int m = 0; m < 4; m++)
            qf[m] = *(const bf16x8*)(qbase + (size_t)(q0 + m * 16 + (lane & 15)) * ND);
    }
    f32x4 lsum[4], vacc[4];
#pragma unroll
    for (int m = 0; m < 4; m++)
#pragma unroll
        for (int r = 0; r < 4; r++) { lsum[m][r] = 0.f; vacc[m][r] = 0.f; }

    const bf* kbase = KL + ((size_t)b * NN) * ND + h * 32;
    for (int kt = 0; kt < 8; kt++) {
        const int k0 = kt * 128;
        __syncthreads();
#pragma unroll
        for (int i = 0; i < 2; i++) {
            int f = t + i * 256;
            int row = ((f >> 6) << 4) + (f & 15);
            int chunk = (f >> 4) & 3;
            *(bf16x8*)&Kf[f * 8] = *(const bf16x8*)(kbase + (size_t)(k0 + row) * ND + chunk * 8);
        }
        if (t < 128) vv[t] = value[(size_t)b * NN + k0 + t];
        __syncthreads();
#pragma unroll
        for (int s = 0; s < 8; s++) {
            bf16x8 bfr = *(const bf16x8*)&Kf[(s * 64 + lane) * 8];
            float vcol = vv[s * 16 + (lane & 15)];
#pragma unroll
            for (int m = 0; m < 4; m++) {
                f32x4 acc = {0.f, 0.f, 0.f, 0.f};
                acc = __builtin_amdgcn_mfma_f32_16x16x32_bf16(qf[m], bfr, acc, 0, 0, 0);
#pragma unroll
                for (int r = 0; r < 4; r++) {
                    float p;
                    asm("v_exp_f32 %0, %1\n\ts_nop 0" : "=v"(p) : "v"(acc[r]));
                    lsum[m][r] += p;
                    vacc[m][r] += p * vcol;
                }
            }
        }
    }
    // epilogue: whole from q.KG (linear in k: sum_l (q.k_l) v_l = q . KG)
    float kgf[8];
#pragma unroll
    for (int j = 0; j < 8; j++) kgf[j] = KG[(size_t)bh * 32 + (lane >> 4) * 8 + j];
    const float lam = lamda[0];
#pragma unroll
    for (int m = 0; m < 4; m++) {
        float dot = 0.f;
#pragma unroll
        for (int j = 0; j < 8; j++) {
            float qj = __uint_as_float(((unsigned int)(unsigned short)qf[m][j]) << 16);
            dot += qj * kgf[j];
        }
        dot += __shfl_xor(dot, 16, 64);
        dot += __shfl_xor(dot, 32, 64);   // lane l now holds full dot for row (l&15)
#pragma unroll
        for (int r = 0; r < 4; r++) {
            float ls = lsum[m][r], va = vacc[m][r];
#pragma unroll
            for (int off = 1; off < 16; off <<= 1) {
                ls += __shfl_xor(ls, off, 64);
                va += __shfl_xor(va, off, 64);
            }
            float dw = __shfl(dot, (lane >> 4) * 4 + r, 64);
            if ((lane & 15) == 0) {
                int q = q0 + m * 16 + (lane >> 4) * 4 + r;
                float part = va / ls;
                float whole = fmaxf(dw * (WHOLE_LN2 / 1024.0f), 0.f);
                float f = ((1.f - lam) * part + lam * whole) * 0.125f;
                atomicAdd(&out[((size_t)b * NN + q) * 8], f);
            }
        }
    }
}

// ---------------- pmms8_k: ONE phase-A stage; grid (8 chunks, 16 batches) x 1024 ----------------
// Folds the mu-reduce (8 partials) into the stage kernel; 128 rows per block.
__global__ __launch_bounds__(1024) void pmms8_k(
    const float* __restrict__ query, const float* __restrict__ mu0a,
    const float* __restrict__ pin, float* __restrict__ pout, int stage)
{
    __shared__ float muT[5 * 256];    // [k][c]
    __shared__ float z_s[128][8];     // [n_local][k]
    __shared__ float red[32];
    __shared__ float red2[256 * 5 * 4]; // [c][k][rg]
    const int chunk = blockIdx.x, b = blockIdx.y;
    const int t = threadIdx.x;
    const int wave = t >> 6, lane = t & 63;

    // ---- mu for this stage ----
    if (stage == 0) {
        for (int idx = t; idx < 1280; idx += 1024)
            muT[idx] = mu0a[(idx & 255) * 5 + (idx >> 8)];
        __syncthreads();
    } else {
        for (int idx = t; idx < 1280; idx += 1024) {
            int k = idx >> 8;
            float s = 0.f, cs = 0.f;
#pragma unroll
            for (int ch = 0; ch < NCH; ch++) {
                const float* pbch = pin + ((size_t)(b * NCH + ch)) * PSTRIDE;
                s  += pbch[idx];
                cs += pbch[1280 + k];
            }
            muT[idx] = s / (1e-6f + cs);
        }
        __syncthreads();
        if (t < 256) {
#pragma unroll
            for (int k = 0; k < 5; k++) {
                float v = muT[k * 256 + t];
                float s = wave_reduce_sum(v * v);
                if (lane == 0) red[wave * 5 + k] = s;
            }
        }
        __syncthreads();
        if (t < 5) red[20 + t] = 1.0f / (1e-6f + sqrtf(red[t] + red[5 + t] + red[10 + t] + red[15 + t]));
        __syncthreads();
        for (int idx = t; idx < 1280; idx += 1024)
            muT[idx] *= red[20 + (idx >> 8)];
        __syncthreads();
    }

    // ---- z-pass: 128 rows, 8 lanes/row ----
    {
        const int n_local = t >> 3, part = t & 7;
        const float* qrow = query + ((size_t)b * NN + chunk * 128 + n_local) * ND + part * 32;
        float lg[5] = {0,0,0,0,0};
#pragma unroll
        for (int c4 = 0; c4 < 32; c4 += 4) {
            float4 qv = *(const float4*)&qrow[c4];
#pragma unroll
            for (int k = 0; k < 5; k++) {
                float4 mv = *(const float4*)&muT[k * 256 + part * 32 + c4];
                lg[k] += qv.x*mv.x + qv.y*mv.y + qv.z*mv.z + qv.w*mv.w;
            }
        }
#pragma unroll
        for (int k = 0; k < 5; k++) {
            lg[k] += __shfl_xor(lg[k], 1, 64);
            lg[k] += __shfl_xor(lg[k], 2, 64);
            lg[k] += __shfl_xor(lg[k], 4, 64);
        }
        float mx = lg[0];
#pragma unroll
        for (int k = 1; k < 5; k++) mx = fmaxf(mx, lg[k]);
        float e[5], ssum = 0.f;
#pragma unroll
        for (int k = 0; k < 5; k++) { e[k] = expf(20.0f * (lg[k] - mx)); ssum += e[k]; }
        float is = 1.0f / ssum;
        if (part == 0) {
#pragma unroll
            for (int k = 0; k < 5; k++) z_s[n_local][k] = e[k] * is;
        }
    }
    __syncthreads();

    // ---- col-pass: thread owns (c = t&255, rg = t>>8); 32 rows each ----
    {
        const int c = t & 255, rg = t >> 8;
        float pa[5] = {0,0,0,0,0};
        const float* qcol = query + ((size_t)b * NN + chunk * 128 + rg * 32) * ND + c;
#pragma unroll 4
        for (int nl = 0; nl < 32; nl++) {
            float qv = qcol[(size_t)nl * ND];
            float4 z4 = *(const float4*)&z_s[rg * 32 + nl][0];
            float z4v = z_s[rg * 32 + nl][4];
            pa[0] += qv * z4.x; pa[1] += qv * z4.y; pa[2] += qv * z4.z;
            pa[3] += qv * z4.w; pa[4] += qv * z4v;
        }
#pragma unroll
        for (int k = 0; k < 5; k++) red2[(c * 5 + k) * 4 + rg] = pa[k];
    }
    __syncthreads();

    float* pb = pout + ((size_t)(b * NCH + chunk)) * PSTRIDE;
    for (int idx = t; idx < 1280; idx += 1024) {
        int c = idx & 255, k = idx >> 8;
        const float* r4 = &red2[(c * 5 + k) * 4];
        pb[idx] = r4[0] + r4[1] + r4[2] + r4[3];
    }
    if (t < 5) {
        float s = 0.f;
#pragma unroll 8
        for (int nl = 0; nl < 128; nl++) s += z_s[nl][t];
        pb[1280 + t] = s;
    }
}

// ---------------- phase B: final reduce + 10 tiny stages, one 64-thread block per batch ----------------
__global__ __launch_bounds__(64) void pmms_b_k(
    const float* __restrict__ pin, const float* __restrict__ mu0b,
    float* __restrict__ m1_ws, float* __restrict__ mu2_ws)
{
    int b = blockIdx.x, lane = threadIdx.x;
    float nd[5][4];
    float cs[5] = {0,0,0,0,0};
#pragma unroll
    for (int n = 0; n < 5; n++)
#pragma unroll
        for (int j = 0; j < 4; j++) nd[n][j] = 0.f;
    for (int ch = 0; ch < NCH; ch++) {
        const float* pb = pin + ((size_t)(b * NCH + ch)) * PSTRIDE;
#pragma unroll
        for (int n = 0; n < 5; n++)
#pragma unroll
            for (int j = 0; j < 4; j++) nd[n][j] += pb[n * 256 + lane + 64 * j];
#pragma unroll
        for (int n = 0; n < 5; n++) cs[n] += pb[1280 + n];
    }
#pragma unroll
    for (int n = 0; n < 5; n++) {
        float inv = 1.0f / (1e-6f + cs[n]);
        float sq = 0.f;
#pragma unroll
        for (int j = 0; j < 4; j++) { nd[n][j] *= inv; sq += nd[n][j] * nd[n][j]; }
        float s = wave_allreduce_sum(sq);
        float nr = 1.0f / (1e-6f + sqrtf(s));
#pragma unroll
        for (int j = 0; j < 4; j++) {
            nd[n][j] *= nr;
            m1_ws[((size_t)b * 5 + n) * 256 + lane + 64 * j] = nd[n][j];
        }
    }
    float mu[2][4];
#pragma unroll
    for (int k = 0; k < 2; k++)
#pragma unroll
        for (int j = 0; j < 4; j++) mu[k][j] = mu0b[(lane + 64 * j) * 2 + k];
    for (int stage = 0; stage < 10; stage++) {
        float z[5][2];
        float colsum0 = 0.f, colsum1 = 0.f;
#pragma unroll
        for (int n = 0; n < 5; n++) {
            float l0 = 0.f, l1 = 0.f;
#pragma unroll
            for (int j = 0; j < 4; j++) { l0 += nd[n][j] * mu[0][j]; l1 += nd[n][j] * mu[1][j]; }
            l0 = wave_allreduce_sum(l0);
            l1 = wave_allreduce_sum(l1);
            float a0 = 20.0f * l0, a1 = 20.0f * l1;
            float mxv = fmaxf(a0, a1);
            float e0 = expf(a0 - mxv), e1 = expf(a1 - mxv);
            float inv = 1.0f / (e0 + e1);
            z[n][0] = e0 * inv; z[n][1] = e1 * inv;
            colsum0 += z[n][0]; colsum1 += z[n][1];
        }
        float i0 = 1.0f / (1e-6f + colsum0), i1 = 1.0f / (1e-6f + colsum1);
#pragma unroll
        for (int k = 0; k < 2; k++) {
            float iv = k ? i1 : i0;
            float sq = 0.f;
            float nm[4];
#pragma unroll
            for (int j = 0; j < 4; j++) {
                float v = 0.f;
#pragma unroll
                for (int n = 0; n < 5; n++) v += nd[n][j] * z[n][k];
                v *= iv;
                nm[j] = v; sq += v * v;
            }
            float s = wave_allreduce_sum(sq);
            float nr = 1.0f / (1e-6f + sqrtf(s));
#pragma unroll
            for (int j = 0; j < 4; j++) mu[k][j] = nm[j] * nr;
        }
    }
#pragma unroll
    for (int k = 0; k < 2; k++)
#pragma unroll
        for (int j = 0; j < 4; j++) mu2_ws[((size_t)b * 2 + k) * 256 + lane + 64 * j] = mu[k][j];
}

// ---------------- P1 = softmax(q.m1), P2 = softmax(q.mu2) ----------------
__global__ __launch_bounds__(256) void pmap_k(
    const float* __restrict__ query, const float* __restrict__ m1_ws,
    const float* __restrict__ mu2_ws, float* __restrict__ P1, float* __restrict__ P2)
{
    __shared__ float ms[7 * 256];
    int b = blockIdx.y;
    int t = threadIdx.x;
    int n = blockIdx.x * 256 + t;
    for (int idx = t; idx < 1280; idx += 256) ms[idx] = m1_ws[(size_t)b * 1280 + idx];
    for (int idx = t; idx < 512; idx += 256) ms[1280 + idx] = mu2_ws[(size_t)b * 512 + idx];
    __syncthreads();
    const float* qrow = query + ((size_t)b * NN + n) * ND;
    float lg[7] = {0,0,0,0,0,0,0};
    for (int c4 = 0; c4 < 256; c4 += 4) {
        float4 qv = *(const float4*)&qrow[c4];
#pragma unroll
        for (int k = 0; k < 7; k++) {
            float4 mv = *(const float4*)&ms[k * 256 + c4];
            lg[k] += qv.x*mv.x + qv.y*mv.y + qv.z*mv.z + qv.w*mv.w;
        }
    }
    float mx = lg[0];
#pragma unroll
    for (int k = 1; k < 5; k++) mx = fmaxf(mx, lg[k]);
    float e[5], ssum = 0.f;
#pragma unroll
    for (int k = 0; k < 5; k++) { e[k] = expf(lg[k] - mx); ssum += e[k]; }
    float is = 1.0f / ssum;
#pragma unroll
    for (int k = 0; k < 5; k++) P1[((size_t)b * 5 + k) * NN + n] = e[k] * is;
    float mx2 = fmaxf(lg[5], lg[6]);
    float e0 = expf(lg[5] - mx2), e1 = expf(lg[6] - mx2);
    float inv = 1.0f / (e0 + e1);
    P2[((size_t)b * 2 + 0) * NN + n] = e0 * inv;
    P2[((size_t)b * 2 + 1) * NN + n] = e1 * inv;
}

// ---------------- node_weight conv: one (b, ch) per block, 3 barriers total ----------------
__global__ __launch_bounds__(1024) void nwconv_k(
    const float* __restrict__ P1, const float* __restrict__ P2,
    const float* __restrict__ w1a, const float* __restrict__ b1a,
    const float* __restrict__ ga,  const float* __restrict__ bea,
    const float* __restrict__ w2a, const float* __restrict__ b2a,
    const float* __restrict__ w1b, const float* __restrict__ b1b,
    const float* __restrict__ gb,  const float* __restrict__ beb,
    const float* __restrict__ w2b, const float* __restrict__ b2b,
    float* __restrict__ out)
{
    __shared__ float img[34 * 34];
    __shared__ float mid[16][34 * 34];
    __shared__ float w1s[144], w2s[144], bs[16], gs[16], bes[16], b2s[1];
    int ch = blockIdx.x, b = blockIdx.y;
    int t = threadIdx.x;
    int i = t >> 5, j = t & 31;
    const float* xsrc = (ch < 5) ? &P1[((size_t)b * 5 + ch) * NN]
                                 : &P2[((size_t)b * 2 + (ch - 5)) * NN];
    if (t < 144) { w1s[t] = (ch < 5 ? w1a : w1b)[t]; w2s[t] = (ch < 5 ? w2a : w2b)[t]; }
    if (t >= 256 && t < 272) {
        int y = t - 256;
        bs[y] = (ch < 5 ? b1a : b1b)[y];
        gs[y] = (ch < 5 ? ga : gb)[y];
        bes[y] = (ch < 5 ? bea : beb)[y];
    }
    if (t == 512) b2s[0] = (ch < 5 ? b2a : b2b)[0];
    for (int idx = t; idx < 1156; idx += 1024) img[idx] = 0.f;
    for (int idx = t; idx < 16 * 1156; idx += 1024) ((float*)mid)[idx] = 0.f;
    __syncthreads();
    float xv = xsrc[t];
    img[(i + 1) * 34 + (j + 1)] = xv;
    __syncthreads();
    float r[9];
#pragma unroll
    for (int dy = 0; dy < 3; dy++)
#pragma unroll
        for (int dx = 0; dx < 3; dx++)
            r[dy * 3 + dx] = img[(i + dy) * 34 + (j + dx)];
    const float bninv = rsqrtf(1.0f + 1e-5f);
#pragma unroll
    for (int oc = 0; oc < 16; oc++) {
        float a = 0.f;
#pragma unroll
        for (int q2 = 0; q2 < 9; q2++) a += w1s[oc * 9 + q2] * r[q2];
        a += bs[oc];
        a = gs[oc] * (a * bninv) + bes[oc];
        a = fmaxf(a, 0.f);
        mid[oc][(i + 1) * 34 + (j + 1)] = a;
    }
    __syncthreads();
    float acc2 = b2s[0];
#pragma unroll
    for (int oc = 0; oc < 16; oc++)
#pragma unroll
        for (int dy = 0; dy < 3; dy++)
#pragma unroll
            for (int dx = 0; dx < 3; dx++)
                acc2 += w2s[oc * 9 + dy * 3 + dx] * mid[oc][(i + dy) * 34 + (j + dx)];
    float sig = 1.0f / (1.0f + expf(-acc2));
    out[((size_t)(b * NN + t)) * 8 + 1 + ch] = xv * sig;
}

extern "C" void kernel_launch(void* const* d_in, const int* in_sizes, int n_in,
                              void* d_out, int out_size, void* d_ws, size_t ws_size,
                              hipStream_t stream) {
    const float* query = (const float*)d_in[0];
    const float* key   = (const float*)d_in[1];
    const float* value = (const float*)d_in[2];
    const float* lamda = (const float*)d_in[3];
    const float* W0 = (const float*)d_in[4];
    const float* b0 = (const float*)d_in[5];
    const float* W1 = (const float*)d_in[6];
    const float* b1 = (const float*)d_in[7];
    const float* mu_a = (const float*)d_in[8];
    const float* mu_b = (const float*)d_in[9];
    const float* nw1_w1 = (const float*)d_in[10];
    const float* nw1_b1 = (const float*)d_in[11];
    const float* nw1_g  = (const float*)d_in[12];
    const float* nw1_be = (const float*)d_in[13];
    const float* nw1_w2 = (const float*)d_in[14];
    const float* nw1_b2 = (const float*)d_in[15];
    const float* nw2_w1 = (const float*)d_in[16];
    const float* nw2_b1 = (const float*)d_in[17];
    const float* nw2_g  = (const float*)d_in[18];
    const float* nw2_be = (const float*)d_in[19];
    const float* nw2_w2 = (const float*)d_in[20];
    const float* nw2_b2 = (const float*)d_in[21];
    float* out = (float*)d_out;

    // ws: QLb [0,8MB) + KLb [8,16MB) as bf16 (attention path).
    bf* QLb = (bf*)d_ws;
    bf* KLb = (bf*)((char*)d_ws + ((size_t)8 << 20));
    // PMMS scratch (~2 MB) OVERLAYS the QLb region. Safe: attn5_k (last consumer of
    // QLb/KLb) completes before the first pmms8_k on the serialized stream.
    float* PA   = (float*)d_ws;
    float* PB   = PA + (size_t)16 * NCH * PSTRIDE;
    float* m1w  = PB + (size_t)16 * NCH * PSTRIDE;
    float* mu2w = m1w + (size_t)16 * 1280;
    float* P1w  = mu2w + (size_t)16 * 512;
    float* P2w  = P1w + (size_t)16 * 5 * 1024;
    // Outside the 16MB QL/KL span: KG (16KB) — NOT overlaid.
    float* KGw = (float*)((char*)d_ws + ((size_t)16 << 20));

    zero_k<<<16, 1024, 0, stream>>>(out);
    gemm2_k<<<dim3(256, 1, 2), 256, 0, stream>>>(query, key, W0, b0, W1, b1, QLb, KLb);
    kg_k<<<128, 256, 0, stream>>>(KLb, value, KGw);
    attn5_k<<<dim3(128, 4), 256, 0, stream>>>(QLb, KLb, value, lamda, KGw, out);

    // stage 0: mu0a -> PA; stages 1..9 ping-pong (9 odd -> output PB)
    pmms8_k<<<dim3(NCH, 16), 1024, 0, stream>>>(query, mu_a, PA, PA, 0);
    for (int s = 1; s < 10; s++) {
        const float* pin = (s & 1) ? PA : PB;
        float* pout      = (s & 1) ? PB : PA;
        pmms8_k<<<dim3(NCH, 16), 1024, 0, stream>>>(query, mu_a, pin, pout, s);
    }
    pmms_b_k<<<16, 64, 0, stream>>>(PB, mu_b, m1w, mu2w);
    pmap_k<<<dim3(4, 16), 256, 0, stream>>>(query, m1w, mu2w, P1w, P2w);
    nwconv_k<<<dim3(7, 16), 1024, 0, stream>>>(P1w, P2w,
                                    nw1_w1, nw1_b1, nw1_g, nw1_be, nw1_w2, nw1_b2,
                                    nw2_w1, nw2_b1, nw2_g, nw2_be, nw2_w2, nw2_b2, out);
}

// Round 9
// 345.211 us; speedup vs baseline: 5.4134x; 1.0362x over previous
//
#include <hip/hip_runtime.h>
#include <hip/hip_bf16.h>
#include <math.h>

#define NN 1024
#define ND 256
#define NCH 16        // chunks per batch in phase A (64 rows per chunk)
#define PSTRIDE 1288  // per-(b,chunk) partial block: 5*256 mu-acc + 5 colsum + pad

typedef __hip_bfloat16 bf;
__device__ __forceinline__ float bf2f(bf h) { return __bfloat162float(h); }

typedef __attribute__((ext_vector_type(8))) short bf16x8;
typedef __attribute__((ext_vector_type(4))) float f32x4;

// alpha = (1/sqrt(32)) * log2(e); folded into QL so attn uses v_exp (2^x) directly.
#define QL_ALPHA 0.25503486216f
#define WHOLE_LN2 0.6931471805599453f

__device__ __forceinline__ float wave_reduce_sum(float v) {
#pragma unroll
    for (int off = 32; off > 0; off >>= 1) v += __shfl_down(v, off, 64);
    return v;
}
__device__ __forceinline__ float wave_allreduce_sum(float v) {
#pragma unroll
    for (int off = 1; off < 64; off <<= 1) v += __shfl_xor(v, off, 64);
    return v;
}

__global__ void zero_k(float* __restrict__ out) {
    int i = blockIdx.x * 1024 + threadIdx.x;
    out[(size_t)i * 8] = 0.f;
}

// ---------------- split-bf16 MFMA GEMM: QL = alpha*(query@W0^T+b0) ; KL = key@W1^T+b1 ----------------
__global__ __launch_bounds__(256) void gemm2_k(
    const float* __restrict__ Aq, const float* __restrict__ Ak,
    const float* __restrict__ W0, const float* __restrict__ b0v,
    const float* __restrict__ W1, const float* __restrict__ b1v,
    bf* __restrict__ QL, bf* __restrict__ KL)
{
    const float* A; const float* Bw; const float* bias; bf* C; float alpha;
    if (blockIdx.z == 0) { A = Aq; Bw = W0; bias = b0v; C = QL; alpha = QL_ALPHA; }
    else                 { A = Ak; Bw = W1; bias = b1v; C = KL; alpha = 1.0f; }
    __shared__ short Ahi[4 * 64 * 8],  Alo[4 * 64 * 8];
    __shared__ short Bhi[16 * 64 * 8], Blo[16 * 64 * 8];
    const int t = threadIdx.x;
    const int wave = t >> 6, lane = t & 63;
    const int m0 = blockIdx.x * 64;

    f32x4 acc[4][4];
#pragma unroll
    for (int m = 0; m < 4; m++)
#pragma unroll
        for (int n = 0; n < 4; n++)
#pragma unroll
            for (int r = 0; r < 4; r++) acc[m][n][r] = 0.f;

    for (int k0 = 0; k0 < 256; k0 += 32) {
        __syncthreads();
        {
            int fm = t >> 6, ls = t & 63;
            const float* src = A + (size_t)(m0 + fm * 16 + (ls & 15)) * 256 + k0 + ((ls >> 4) * 8);
            float4 x = *(const float4*)src;
            float4 y = *(const float4*)(src + 4);
            float v[8] = {x.x, x.y, x.z, x.w, y.x, y.y, y.z, y.w};
            short h[8], l8[8];
#pragma unroll
            for (int j = 0; j < 8; j++) {
                bf hb = __float2bfloat16(v[j]);
                float hf = __bfloat162float(hb);
                bf lb = __float2bfloat16(v[j] - hf);
                h[j] = *(short*)&hb; l8[j] = *(short*)&lb;
            }
            *(bf16x8*)&Ahi[t * 8] = *(bf16x8*)h;
            *(bf16x8*)&Alo[t * 8] = *(bf16x8*)l8;
        }
#pragma unroll
        for (int i = 0; i < 4; i++) {
            int idx = t + i * 256;
            int nf = idx >> 6, ls = idx & 63;
            const float* src = Bw + (size_t)(nf * 16 + (ls & 15)) * 256 + k0 + ((ls >> 4) * 8);
            float4 x = *(const float4*)src;
            float4 y = *(const float4*)(src + 4);
            float v[8] = {x.x, x.y, x.z, x.w, y.x, y.y, y.z, y.w};
            short h[8], l8[8];
#pragma unroll
            for (int j = 0; j < 8; j++) {
                bf hb = __float2bfloat16(v[j]);
                float hf = __bfloat162float(hb);
                bf lb = __float2bfloat16(v[j] - hf);
                h[j] = *(short*)&hb; l8[j] = *(short*)&lb;
            }
            *(bf16x8*)&Bhi[idx * 8] = *(bf16x8*)h;
            *(bf16x8*)&Blo[idx * 8] = *(bf16x8*)l8;
        }
        __syncthreads();
        bf16x8 ah[4], al[4], bh[4], bl[4];
#pragma unroll
        for (int m = 0; m < 4; m++) {
            ah[m] = *(const bf16x8*)&Ahi[(m * 64 + lane) * 8];
            al[m] = *(const bf16x8*)&Alo[(m * 64 + lane) * 8];
        }
#pragma unroll
        for (int n = 0; n < 4; n++) {
            int nf = wave * 4 + n;
            bh[n] = *(const bf16x8*)&Bhi[(nf * 64 + lane) * 8];
            bl[n] = *(const bf16x8*)&Blo[(nf * 64 + lane) * 8];
        }
#pragma unroll
        for (int m = 0; m < 4; m++)
#pragma unroll
            for (int n = 0; n < 4; n++) {
                acc[m][n] = __builtin_amdgcn_mfma_f32_16x16x32_bf16(ah[m], bh[n], acc[m][n], 0, 0, 0);
                acc[m][n] = __builtin_amdgcn_mfma_f32_16x16x32_bf16(ah[m], bl[n], acc[m][n], 0, 0, 0);
                acc[m][n] = __builtin_amdgcn_mfma_f32_16x16x32_bf16(al[m], bh[n], acc[m][n], 0, 0, 0);
            }
    }
#pragma unroll
    for (int n = 0; n < 4; n++) {
        int col = (wave * 4 + n) * 16 + (lane & 15);
        float bv = bias[col];
#pragma unroll
        for (int m = 0; m < 4; m++) {
            int row = m0 + m * 16 + (lane >> 4) * 4;
#pragma unroll
            for (int r = 0; r < 4; r++) {
                bf hv = __float2bfloat16((acc[m][n][r] + bv) * alpha);
                C[(size_t)(row + r) * 256 + col] = hv;
            }
        }
    }
}

// ---------------- KG[b][h][c] = sum_l KL[b,l,h*32+c] * value[b,l] ----------------
__global__ __launch_bounds__(256) void kg_k(
    const bf* __restrict__ KL, const float* __restrict__ value, float* __restrict__ KG)
{
    const int bh = blockIdx.x, b = bh >> 3, h = bh & 7;
    const int t = threadIdx.x;
    const int c = t & 31, rg = t >> 5;   // 8 row-groups of 128 rows
    float acc = 0.f;
    const bf* kp = KL + (size_t)b * NN * ND + h * 32 + c;
    const float* vp = value + (size_t)b * NN;
#pragma unroll 8
    for (int r = rg * 128; r < rg * 128 + 128; r++)
        acc += bf2f(kp[(size_t)r * ND]) * vp[r];
    __shared__ float kgs[8][33];
    kgs[rg][c] = acc;
    __syncthreads();
    if (t < 32) {
        float s = 0.f;
#pragma unroll
        for (int g = 0; g < 8; g++) s += kgs[g][t];
        KG[(size_t)bh * 32 + t] = s;
    }
}

// ---------------- MFMA flash attention: 64 q-rows/wave, v_exp inner, KG-based whole ----------------
__global__ __launch_bounds__(256) void attn5_k(
    const bf* __restrict__ QL, const bf* __restrict__ KL,
    const float* __restrict__ value, const float* __restrict__ lamda,
    const float* __restrict__ KG, float* __restrict__ out)
{
    const int bh = blockIdx.x; const int b = bh >> 3, h = bh & 7;
    const int t = threadIdx.x;
    const int wave = t >> 6, lane = t & 63;
    const int q0 = blockIdx.y * 256 + wave * 64;

    __shared__ bf Kf[128 * 32];   // 512 fragments * 8 bf16, fragment order
    __shared__ float vv[128];

    bf16x8 qf[4];
    {
        const bf* qbase = QL + ((size_t)b * NN) * ND + h * 32 + (lane >> 4) * 8;
#pragma unroll
        for (int m = 0; m < 4; m++)
            qf[m] = *(const bf16x8*)(qbase + (size_t)(q0 + m * 16 + (lane & 15)) * ND);
    }
    f32x4 lsum[4], vacc[4];
#pragma unroll
    for (int m = 0; m < 4; m++)
#pragma unroll
        for (int r = 0; r < 4; r++) { lsum[m][r] = 0.f; vacc[m][r] = 0.f; }

    const bf* kbase = KL + ((size_t)b * NN) * ND + h * 32;
    for (int kt = 0; kt < 8; kt++) {
        const int k0 = kt * 128;
        __syncthreads();
#pragma unroll
        for (int i = 0; i < 2; i++) {
            int f = t + i * 256;
            int row = ((f >> 6) << 4) + (f & 15);
            int chunk = (f >> 4) & 3;
            *(bf16x8*)&Kf[f * 8] = *(const bf16x8*)(kbase + (size_t)(k0 + row) * ND + chunk * 8);
        }
        if (t < 128) vv[t] = value[(size_t)b * NN + k0 + t];
        __syncthreads();
#pragma unroll
        for (int s = 0; s < 8; s++) {
            bf16x8 bfr = *(const bf16x8*)&Kf[(s * 64 + lane) * 8];
            float vcol = vv[s * 16 + (lane & 15)];
#pragma unroll
            for (int m = 0; m < 4; m++) {
                f32x4 acc = {0.f, 0.f, 0.f, 0.f};
                acc = __builtin_amdgcn_mfma_f32_16x16x32_bf16(qf[m], bfr, acc, 0, 0, 0);
#pragma unroll
                for (int r = 0; r < 4; r++) {
                    float p;
                    asm("v_exp_f32 %0, %1\n\ts_nop 0" : "=v"(p) : "v"(acc[r]));
                    lsum[m][r] += p;
                    vacc[m][r] += p * vcol;
                }
            }
        }
    }
    // epilogue: whole from q.KG (linear in k: sum_l (q.k_l) v_l = q . KG)
    float kgf[8];
#pragma unroll
    for (int j = 0; j < 8; j++) kgf[j] = KG[(size_t)bh * 32 + (lane >> 4) * 8 + j];
    const float lam = lamda[0];
#pragma unroll
    for (int m = 0; m < 4; m++) {
        float dot = 0.f;
#pragma unroll
        for (int j = 0; j < 8; j++) {
            float qj = __uint_as_float(((unsigned int)(unsigned short)qf[m][j]) << 16);
            dot += qj * kgf[j];
        }
        dot += __shfl_xor(dot, 16, 64);
        dot += __shfl_xor(dot, 32, 64);   // lane l now holds full dot for row (l&15)
#pragma unroll
        for (int r = 0; r < 4; r++) {
            float ls = lsum[m][r], va = vacc[m][r];
#pragma unroll
            for (int off = 1; off < 16; off <<= 1) {
                ls += __shfl_xor(ls, off, 64);
                va += __shfl_xor(va, off, 64);
            }
            float dw = __shfl(dot, (lane >> 4) * 4 + r, 64);
            if ((lane & 15) == 0) {
                int q = q0 + m * 16 + (lane >> 4) * 4 + r;
                float part = va / ls;
                float whole = fmaxf(dw * (WHOLE_LN2 / 1024.0f), 0.f);
                float f = ((1.f - lam) * part + lam * whole) * 0.125f;
                atomicAdd(&out[((size_t)b * NN + q) * 8], f);
            }
        }
    }
}

// ---------------- pmms16_k: ONE phase-A stage; grid (16 chunks, 16 batches) x 1024 ----------------
// 64-row chunks, 16 lanes/row in the z-pass (all 1024 threads active); fused mu-reduce.
__global__ __launch_bounds__(1024) void pmms16_k(
    const float* __restrict__ query, const float* __restrict__ mu0a,
    const float* __restrict__ pin, float* __restrict__ pout, int stage)
{
    __shared__ float muT[5 * 256];      // [k][c]
    __shared__ float z_s[64][8];        // [n_local][k]
    __shared__ float red[32];
    __shared__ float red2[256 * 5 * 4]; // [c][k][rg]
    const int chunk = blockIdx.x, b = blockIdx.y;
    const int t = threadIdx.x;
    const int wave = t >> 6, lane = t & 63;

    // ---- mu for this stage (reduce NCH partials, colsum-normalize, l2-normalize) ----
    if (stage == 0) {
        for (int idx = t; idx < 1280; idx += 1024)
            muT[idx] = mu0a[(idx & 255) * 5 + (idx >> 8)];
        __syncthreads();
    } else {
        for (int idx = t; idx < 1280; idx += 1024) {
            int k = idx >> 8;
            float s = 0.f, cs = 0.f;
            for (int ch = 0; ch < NCH; ch++) {
                const float* pbch = pin + ((size_t)(b * NCH + ch)) * PSTRIDE;
                s  += pbch[idx];
                cs += pbch[1280 + k];
            }
            muT[idx] = s / (1e-6f + cs);
        }
        __syncthreads();
        if (t < 256) {
#pragma unroll
            for (int k = 0; k < 5; k++) {
                float v = muT[k * 256 + t];
                float s = wave_reduce_sum(v * v);
                if (lane == 0) red[wave * 5 + k] = s;
            }
        }
        __syncthreads();
        if (t < 5) red[20 + t] = 1.0f / (1e-6f + sqrtf(red[t] + red[5 + t] + red[10 + t] + red[15 + t]));
        __syncthreads();
        for (int idx = t; idx < 1280; idx += 1024)
            muT[idx] *= red[20 + (idx >> 8)];
        __syncthreads();
    }

    // ---- z-pass: 64 rows, 16 lanes/row (all threads active) ----
    {
        const int n_local = t >> 4, part = t & 15;
        const float* qrow = query + ((size_t)b * NN + chunk * 64 + n_local) * ND + part * 16;
        float lg[5] = {0,0,0,0,0};
#pragma unroll
        for (int c4 = 0; c4 < 16; c4 += 4) {
            float4 qv = *(const float4*)&qrow[c4];
#pragma unroll
            for (int k = 0; k < 5; k++) {
                float4 mv = *(const float4*)&muT[k * 256 + part * 16 + c4];
                lg[k] += qv.x*mv.x + qv.y*mv.y + qv.z*mv.z + qv.w*mv.w;
            }
        }
#pragma unroll
        for (int k = 0; k < 5; k++) {
            lg[k] += __shfl_xor(lg[k], 1, 64);
            lg[k] += __shfl_xor(lg[k], 2, 64);
            lg[k] += __shfl_xor(lg[k], 4, 64);
            lg[k] += __shfl_xor(lg[k], 8, 64);
        }
        float mx = lg[0];
#pragma unroll
        for (int k = 1; k < 5; k++) mx = fmaxf(mx, lg[k]);
        float e[5], ssum = 0.f;
#pragma unroll
        for (int k = 0; k < 5; k++) { e[k] = expf(20.0f * (lg[k] - mx)); ssum += e[k]; }
        float is = 1.0f / ssum;
        if (part == 0) {
#pragma unroll
            for (int k = 0; k < 5; k++) z_s[n_local][k] = e[k] * is;
        }
    }
    __syncthreads();

    // ---- col-pass: thread owns (c = t&255, rg = t>>8); 16 rows each ----
    {
        const int c = t & 255, rg = t >> 8;
        float pa[5] = {0,0,0,0,0};
        const float* qcol = query + ((size_t)b * NN + chunk * 64 + rg * 16) * ND + c;
#pragma unroll 4
        for (int nl = 0; nl < 16; nl++) {
            float qv = qcol[(size_t)nl * ND];
            float4 z4 = *(const float4*)&z_s[rg * 16 + nl][0];
            float z4v = z_s[rg * 16 + nl][4];
            pa[0] += qv * z4.x; pa[1] += qv * z4.y; pa[2] += qv * z4.z;
            pa[3] += qv * z4.w; pa[4] += qv * z4v;
        }
#pragma unroll
        for (int k = 0; k < 5; k++) red2[(c * 5 + k) * 4 + rg] = pa[k];
    }
    __syncthreads();

    float* pb = pout + ((size_t)(b * NCH + chunk)) * PSTRIDE;
    for (int idx = t; idx < 1280; idx += 1024) {
        int c = idx & 255, k = idx >> 8;
        const float* r4 = &red2[(c * 5 + k) * 4];
        pb[idx] = r4[0] + r4[1] + r4[2] + r4[3];
    }
    if (t < 5) {
        float s = 0.f;
#pragma unroll 8
        for (int nl = 0; nl < 64; nl++) s += z_s[nl][t];
        pb[1280 + t] = s;
    }
}

// ---------------- phase B: final reduce + 10 tiny stages, one 64-thread block per batch ----------------
__global__ __launch_bounds__(64) void pmms_b_k(
    const float* __restrict__ pin, const float* __restrict__ mu0b,
    float* __restrict__ m1_ws, float* __restrict__ mu2_ws)
{
    int b = blockIdx.x, lane = threadIdx.x;
    float nd[5][4];
    float cs[5] = {0,0,0,0,0};
#pragma unroll
    for (int n = 0; n < 5; n++)
#pragma unroll
        for (int j = 0; j < 4; j++) nd[n][j] = 0.f;
    for (int ch = 0; ch < NCH; ch++) {
        const float* pb = pin + ((size_t)(b * NCH + ch)) * PSTRIDE;
#pragma unroll
        for (int n = 0; n < 5; n++)
#pragma unroll
            for (int j = 0; j < 4; j++) nd[n][j] += pb[n * 256 + lane + 64 * j];
#pragma unroll
        for (int n = 0; n < 5; n++) cs[n] += pb[1280 + n];
    }
#pragma unroll
    for (int n = 0; n < 5; n++) {
        float inv = 1.0f / (1e-6f + cs[n]);
        float sq = 0.f;
#pragma unroll
        for (int j = 0; j < 4; j++) { nd[n][j] *= inv; sq += nd[n][j] * nd[n][j]; }
        float s = wave_allreduce_sum(sq);
        float nr = 1.0f / (1e-6f + sqrtf(s));
#pragma unroll
        for (int j = 0; j < 4; j++) {
            nd[n][j] *= nr;
            m1_ws[((size_t)b * 5 + n) * 256 + lane + 64 * j] = nd[n][j];
        }
    }
    float mu[2][4];
#pragma unroll
    for (int k = 0; k < 2; k++)
#pragma unroll
        for (int j = 0; j < 4; j++) mu[k][j] = mu0b[(lane + 64 * j) * 2 + k];
    for (int stage = 0; stage < 10; stage++) {
        float z[5][2];
        float colsum0 = 0.f, colsum1 = 0.f;
#pragma unroll
        for (int n = 0; n < 5; n++) {
            float l0 = 0.f, l1 = 0.f;
#pragma unroll
            for (int j = 0; j < 4; j++) { l0 += nd[n][j] * mu[0][j]; l1 += nd[n][j] * mu[1][j]; }
            l0 = wave_allreduce_sum(l0);
            l1 = wave_allreduce_sum(l1);
            float a0 = 20.0f * l0, a1 = 20.0f * l1;
            float mxv = fmaxf(a0, a1);
            float e0 = expf(a0 - mxv), e1 = expf(a1 - mxv);
            float inv = 1.0f / (e0 + e1);
            z[n][0] = e0 * inv; z[n][1] = e1 * inv;
            colsum0 += z[n][0]; colsum1 += z[n][1];
        }
        float i0 = 1.0f / (1e-6f + colsum0), i1 = 1.0f / (1e-6f + colsum1);
#pragma unroll
        for (int k = 0; k < 2; k++) {
            float iv = k ? i1 : i0;
            float sq = 0.f;
            float nm[4];
#pragma unroll
            for (int j = 0; j < 4; j++) {
                float v = 0.f;
#pragma unroll
                for (int n = 0; n < 5; n++) v += nd[n][j] * z[n][k];
                v *= iv;
                nm[j] = v; sq += v * v;
            }
            float s = wave_allreduce_sum(sq);
            float nr = 1.0f / (1e-6f + sqrtf(s));
#pragma unroll
            for (int j = 0; j < 4; j++) mu[k][j] = nm[j] * nr;
        }
    }
#pragma unroll
    for (int k = 0; k < 2; k++)
#pragma unroll
        for (int j = 0; j < 4; j++) mu2_ws[((size_t)b * 2 + k) * 256 + lane + 64 * j] = mu[k][j];
}

// ---------------- P1 = softmax(q.m1), P2 = softmax(q.mu2) ----------------
__global__ __launch_bounds__(256) void pmap_k(
    const float* __restrict__ query, const float* __restrict__ m1_ws,
    const float* __restrict__ mu2_ws, float* __restrict__ P1, float* __restrict__ P2)
{
    __shared__ float ms[7 * 256];
    int b = blockIdx.y;
    int t = threadIdx.x;
    int n = blockIdx.x * 256 + t;
    for (int idx = t; idx < 1280; idx += 256) ms[idx] = m1_ws[(size_t)b * 1280 + idx];
    for (int idx = t; idx < 512; idx += 256) ms[1280 + idx] = mu2_ws[(size_t)b * 512 + idx];
    __syncthreads();
    const float* qrow = query + ((size_t)b * NN + n) * ND;
    float lg[7] = {0,0,0,0,0,0,0};
    for (int c4 = 0; c4 < 256; c4 += 4) {
        float4 qv = *(const float4*)&qrow[c4];
#pragma unroll
        for (int k = 0; k < 7; k++) {
            float4 mv = *(const float4*)&ms[k * 256 + c4];
            lg[k] += qv.x*mv.x + qv.y*mv.y + qv.z*mv.z + qv.w*mv.w;
        }
    }
    float mx = lg[0];
#pragma unroll
    for (int k = 1; k < 5; k++) mx = fmaxf(mx, lg[k]);
    float e[5], ssum = 0.f;
#pragma unroll
    for (int k = 0; k < 5; k++) { e[k] = expf(lg[k] - mx); ssum += e[k]; }
    float is = 1.0f / ssum;
#pragma unroll
    for (int k = 0; k < 5; k++) P1[((size_t)b * 5 + k) * NN + n] = e[k] * is;
    float mx2 = fmaxf(lg[5], lg[6]);
    float e0 = expf(lg[5] - mx2), e1 = expf(lg[6] - mx2);
    float inv = 1.0f / (e0 + e1);
    P2[((size_t)b * 2 + 0) * NN + n] = e0 * inv;
    P2[((size_t)b * 2 + 1) * NN + n] = e1 * inv;
}

// ---------------- node_weight conv: one (b, ch) per block ----------------
__global__ __launch_bounds__(1024) void nwconv_k(
    const float* __restrict__ P1, const float* __restrict__ P2,
    const float* __restrict__ w1a, const float* __restrict__ b1a,
    const float* __restrict__ ga,  const float* __restrict__ bea,
    const float* __restrict__ w2a, const float* __restrict__ b2a,
    const float* __restrict__ w1b, const float* __restrict__ b1b,
    const float* __restrict__ gb,  const float* __restrict__ beb,
    const float* __restrict__ w2b, const float* __restrict__ b2b,
    float* __restrict__ out)
{
    __shared__ float img[34 * 34];
    __shared__ float mid[16][34 * 34];
    __shared__ float w1s[144], w2s[144], bs[16], gs[16], bes[16], b2s[1];
    int ch = blockIdx.x, b = blockIdx.y;
    int t = threadIdx.x;
    int i = t >> 5, j = t & 31;
    const float* xsrc = (ch < 5) ? &P1[((size_t)b * 5 + ch) * NN]
                                 : &P2[((size_t)b * 2 + (ch - 5)) * NN];
    if (t < 144) { w1s[t] = (ch < 5 ? w1a : w1b)[t]; w2s[t] = (ch < 5 ? w2a : w2b)[t]; }
    if (t >= 256 && t < 272) {
        int y = t - 256;
        bs[y] = (ch < 5 ? b1a : b1b)[y];
        gs[y] = (ch < 5 ? ga : gb)[y];
        bes[y] = (ch < 5 ? bea : beb)[y];
    }
    if (t == 512) b2s[0] = (ch < 5 ? b2a : b2b)[0];
    for (int idx = t; idx < 1156; idx += 1024) img[idx] = 0.f;
    for (int idx = t; idx < 16 * 1156; idx += 1024) ((float*)mid)[idx] = 0.f;
    __syncthreads();
    float xv = xsrc[t];
    img[(i + 1) * 34 + (j + 1)] = xv;
    __syncthreads();
    float r[9];
#pragma unroll
    for (int dy = 0; dy < 3; dy++)
#pragma unroll
        for (int dx = 0; dx < 3; dx++)
            r[dy * 3 + dx] = img[(i + dy) * 34 + (j + dx)];
    const float bninv = rsqrtf(1.0f + 1e-5f);
#pragma unroll
    for (int oc = 0; oc < 16; oc++) {
        float a = 0.f;
#pragma unroll
        for (int q2 = 0; q2 < 9; q2++) a += w1s[oc * 9 + q2] * r[q2];
        a += bs[oc];
        a = gs[oc] * (a * bninv) + bes[oc];
        a = fmaxf(a, 0.f);
        mid[oc][(i + 1) * 34 + (j + 1)] = a;
    }
    __syncthreads();
    float acc2 = b2s[0];
#pragma unroll
    for (int oc = 0; oc < 16; oc++)
#pragma unroll
        for (int dy = 0; dy < 3; dy++)
#pragma unroll
            for (int dx = 0; dx < 3; dx++)
                acc2 += w2s[oc * 9 + dy * 3 + dx] * mid[oc][(i + dy) * 34 + (j + dx)];
    float sig = 1.0f / (1.0f + expf(-acc2));
    out[((size_t)(b * NN + t)) * 8 + 1 + ch] = xv * sig;
}

extern "C" void kernel_launch(void* const* d_in, const int* in_sizes, int n_in,
                              void* d_out, int out_size, void* d_ws, size_t ws_size,
                              hipStream_t stream) {
    const float* query = (const float*)d_in[0];
    const float* key   = (const float*)d_in[1];
    const float* value = (const float*)d_in[2];
    const float* lamda = (const float*)d_in[3];
    const float* W0 = (const float*)d_in[4];
    const float* b0 = (const float*)d_in[5];
    const float* W1 = (const float*)d_in[6];
    const float* b1 = (const float*)d_in[7];
    const float* mu_a = (const float*)d_in[8];
    const float* mu_b = (const float*)d_in[9];
    const float* nw1_w1 = (const float*)d_in[10];
    const float* nw1_b1 = (const float*)d_in[11];
    const float* nw1_g  = (const float*)d_in[12];
    const float* nw1_be = (const float*)d_in[13];
    const float* nw1_w2 = (const float*)d_in[14];
    const float* nw1_b2 = (const float*)d_in[15];
    const float* nw2_w1 = (const float*)d_in[16];
    const float* nw2_b1 = (const float*)d_in[17];
    const float* nw2_g  = (const float*)d_in[18];
    const float* nw2_be = (const float*)d_in[19];
    const float* nw2_w2 = (const float*)d_in[20];
    const float* nw2_b2 = (const float*)d_in[21];
    float* out = (float*)d_out;

    // ws: QLb [0,8MB) + KLb [8,16MB) as bf16 (attention path).
    bf* QLb = (bf*)d_ws;
    bf* KLb = (bf*)((char*)d_ws + ((size_t)8 << 20));
    // PMMS scratch (~3.5 MB) OVERLAYS the QLb region. Safe: attn5_k (last consumer of
    // QLb/KLb) completes before the first pmms16_k on the serialized stream.
    float* PA   = (float*)d_ws;
    float* PB   = PA + (size_t)16 * NCH * PSTRIDE;
    float* m1w  = PB + (size_t)16 * NCH * PSTRIDE;
    float* mu2w = m1w + (size_t)16 * 1280;
    float* P1w  = mu2w + (size_t)16 * 512;
    float* P2w  = P1w + (size_t)16 * 5 * 1024;
    // Outside the 16MB QL/KL span: KG (16KB) — NOT overlaid.
    float* KGw = (float*)((char*)d_ws + ((size_t)16 << 20));

    zero_k<<<16, 1024, 0, stream>>>(out);
    gemm2_k<<<dim3(256, 1, 2), 256, 0, stream>>>(query, key, W0, b0, W1, b1, QLb, KLb);
    kg_k<<<128, 256, 0, stream>>>(KLb, value, KGw);
    attn5_k<<<dim3(128, 4), 256, 0, stream>>>(QLb, KLb, value, lamda, KGw, out);

    // stage 0: mu0a -> PA; stages 1..9 ping-pong (9 odd -> output PB)
    pmms16_k<<<dim3(NCH, 16), 1024, 0, stream>>>(query, mu_a, PA, PA, 0);
    for (int s = 1; s < 10; s++) {
        const float* pin = (s & 1) ? PA : PB;
        float* pout      = (s & 1) ? PB : PA;
        pmms16_k<<<dim3(NCH, 16), 1024, 0, stream>>>(query, mu_a, pin, pout, s);
    }
    pmms_b_k<<<16, 64, 0, stream>>>(PB, mu_b, m1w, mu2w);
    pmap_k<<<dim3(4, 16), 256, 0, stream>>>(query, m1w, mu2w, P1w, P2w);
    nwconv_k<<<dim3(7, 16), 1024, 0, stream>>>(P1w, P2w,
                                    nw1_w1, nw1_b1, nw1_g, nw1_be, nw1_w2, nw1_b2,
                                    nw2_w1, nw2_b1, nw2_g, nw2_be, nw2_w2, nw2_b2, out);
}

// Round 10
// 341.685 us; speedup vs baseline: 5.4693x; 1.0103x over previous
//
#include <hip/hip_runtime.h>
#include <hip/hip_bf16.h>
#include <math.h>

#define NN 1024
#define ND 256
#define NCH 16        // chunks per batch in phase A (64 rows per chunk)
#define PSTRIDE 1288  // per-(b,chunk) partial block: 5*256 mu-acc + 5 colsum + pad

typedef __hip_bfloat16 bf;
__device__ __forceinline__ float bf2f(bf h) { return __bfloat162float(h); }

typedef __attribute__((ext_vector_type(8))) short bf16x8;
typedef __attribute__((ext_vector_type(4))) float f32x4;

// alpha = (1/sqrt(32)) * log2(e); folded into QL so attn uses v_exp (2^x) directly.
#define QL_ALPHA 0.25503486216f
#define WHOLE_LN2 0.6931471805599453f

__device__ __forceinline__ float wave_reduce_sum(float v) {
#pragma unroll
    for (int off = 32; off > 0; off >>= 1) v += __shfl_down(v, off, 64);
    return v;
}
__device__ __forceinline__ float wave_allreduce_sum(float v) {
#pragma unroll
    for (int off = 1; off < 64; off <<= 1) v += __shfl_xor(v, off, 64);
    return v;
}

// ---------------- split-bf16 MFMA GEMM: QL = alpha*(query@W0^T+b0) ; KL = key@W1^T+b1 ----------------
__global__ __launch_bounds__(256) void gemm2_k(
    const float* __restrict__ Aq, const float* __restrict__ Ak,
    const float* __restrict__ W0, const float* __restrict__ b0v,
    const float* __restrict__ W1, const float* __restrict__ b1v,
    bf* __restrict__ QL, bf* __restrict__ KL)
{
    const float* A; const float* Bw; const float* bias; bf* C; float alpha;
    if (blockIdx.z == 0) { A = Aq; Bw = W0; bias = b0v; C = QL; alpha = QL_ALPHA; }
    else                 { A = Ak; Bw = W1; bias = b1v; C = KL; alpha = 1.0f; }
    __shared__ short Ahi[4 * 64 * 8],  Alo[4 * 64 * 8];
    __shared__ short Bhi[16 * 64 * 8], Blo[16 * 64 * 8];
    const int t = threadIdx.x;
    const int wave = t >> 6, lane = t & 63;
    const int m0 = blockIdx.x * 64;

    f32x4 acc[4][4];
#pragma unroll
    for (int m = 0; m < 4; m++)
#pragma unroll
        for (int n = 0; n < 4; n++)
#pragma unroll
            for (int r = 0; r < 4; r++) acc[m][n][r] = 0.f;

    for (int k0 = 0; k0 < 256; k0 += 32) {
        __syncthreads();
        {
            int fm = t >> 6, ls = t & 63;
            const float* src = A + (size_t)(m0 + fm * 16 + (ls & 15)) * 256 + k0 + ((ls >> 4) * 8);
            float4 x = *(const float4*)src;
            float4 y = *(const float4*)(src + 4);
            float v[8] = {x.x, x.y, x.z, x.w, y.x, y.y, y.z, y.w};
            short h[8], l8[8];
#pragma unroll
            for (int j = 0; j < 8; j++) {
                bf hb = __float2bfloat16(v[j]);
                float hf = __bfloat162float(hb);
                bf lb = __float2bfloat16(v[j] - hf);
                h[j] = *(short*)&hb; l8[j] = *(short*)&lb;
            }
            *(bf16x8*)&Ahi[t * 8] = *(bf16x8*)h;
            *(bf16x8*)&Alo[t * 8] = *(bf16x8*)l8;
        }
#pragma unroll
        for (int i = 0; i < 4; i++) {
            int idx = t + i * 256;
            int nf = idx >> 6, ls = idx & 63;
            const float* src = Bw + (size_t)(nf * 16 + (ls & 15)) * 256 + k0 + ((ls >> 4) * 8);
            float4 x = *(const float4*)src;
            float4 y = *(const float4*)(src + 4);
            float v[8] = {x.x, x.y, x.z, x.w, y.x, y.y, y.z, y.w};
            short h[8], l8[8];
#pragma unroll
            for (int j = 0; j < 8; j++) {
                bf hb = __float2bfloat16(v[j]);
                float hf = __bfloat162float(hb);
                bf lb = __float2bfloat16(v[j] - hf);
                h[j] = *(short*)&hb; l8[j] = *(short*)&lb;
            }
            *(bf16x8*)&Bhi[idx * 8] = *(bf16x8*)h;
            *(bf16x8*)&Blo[idx * 8] = *(bf16x8*)l8;
        }
        __syncthreads();
        bf16x8 ah[4], al[4], bh[4], bl[4];
#pragma unroll
        for (int m = 0; m < 4; m++) {
            ah[m] = *(const bf16x8*)&Ahi[(m * 64 + lane) * 8];
            al[m] = *(const bf16x8*)&Alo[(m * 64 + lane) * 8];
        }
#pragma unroll
        for (int n = 0; n < 4; n++) {
            int nf = wave * 4 + n;
            bh[n] = *(const bf16x8*)&Bhi[(nf * 64 + lane) * 8];
            bl[n] = *(const bf16x8*)&Blo[(nf * 64 + lane) * 8];
        }
#pragma unroll
        for (int m = 0; m < 4; m++)
#pragma unroll
            for (int n = 0; n < 4; n++) {
                acc[m][n] = __builtin_amdgcn_mfma_f32_16x16x32_bf16(ah[m], bh[n], acc[m][n], 0, 0, 0);
                acc[m][n] = __builtin_amdgcn_mfma_f32_16x16x32_bf16(ah[m], bl[n], acc[m][n], 0, 0, 0);
                acc[m][n] = __builtin_amdgcn_mfma_f32_16x16x32_bf16(al[m], bh[n], acc[m][n], 0, 0, 0);
            }
    }
#pragma unroll
    for (int n = 0; n < 4; n++) {
        int col = (wave * 4 + n) * 16 + (lane & 15);
        float bv = bias[col];
#pragma unroll
        for (int m = 0; m < 4; m++) {
            int row = m0 + m * 16 + (lane >> 4) * 4;
#pragma unroll
            for (int r = 0; r < 4; r++) {
                bf hv = __float2bfloat16((acc[m][n][r] + bv) * alpha);
                C[(size_t)(row + r) * 256 + col] = hv;
            }
        }
    }
}

// ---------------- KG[b][h][c] = sum_l KL[b,l,h*32+c] * value[b,l]; also zeroes out ch0 ----------------
__global__ __launch_bounds__(256) void kg_k(
    const bf* __restrict__ KL, const float* __restrict__ value, float* __restrict__ KG,
    float* __restrict__ out)
{
    const int bh = blockIdx.x, b = bh >> 3, h = bh & 7;
    const int t = threadIdx.x;
    // zero out channel 0 (rows h*128..h*128+127 of batch b) — exact 1:1 cover over grid
    if (t < 128) out[((size_t)b * NN + h * 128 + t) * 8] = 0.f;
    const int c = t & 31, rg = t >> 5;   // 8 row-groups of 128 rows
    float acc = 0.f;
    const bf* kp = KL + (size_t)b * NN * ND + h * 32 + c;
    const float* vp = value + (size_t)b * NN;
#pragma unroll 8
    for (int r = rg * 128; r < rg * 128 + 128; r++)
        acc += bf2f(kp[(size_t)r * ND]) * vp[r];
    __shared__ float kgs[8][33];
    kgs[rg][c] = acc;
    __syncthreads();
    if (t < 32) {
        float s = 0.f;
#pragma unroll
        for (int g = 0; g < 8; g++) s += kgs[g][t];
        KG[(size_t)bh * 32 + t] = s;
    }
}

// ---------------- MFMA flash attention: 32 q-rows/wave (grid 128x8 -> 4 waves/SIMD),
//                  v_exp inner, KG-based whole ----------------
__global__ __launch_bounds__(256) void attn5_k(
    const bf* __restrict__ QL, const bf* __restrict__ KL,
    const float* __restrict__ value, const float* __restrict__ lamda,
    const float* __restrict__ KG, float* __restrict__ out)
{
    const int bh = blockIdx.x; const int b = bh >> 3, h = bh & 7;
    const int t = threadIdx.x;
    const int wave = t >> 6, lane = t & 63;
    const int q0 = blockIdx.y * 128 + wave * 32;

    __shared__ bf Kf[128 * 32];   // 512 fragments * 8 bf16, fragment order
    __shared__ float vv[128];

    bf16x8 qf[2];
    {
        const bf* qbase = QL + ((size_t)b * NN) * ND + h * 32 + (lane >> 4) * 8;
#pragma unroll
        for (int m = 0; m < 2; m++)
            qf[m] = *(const bf16x8*)(qbase + (size_t)(q0 + m * 16 + (lane & 15)) * ND);
    }
    f32x4 lsum[2], vacc[2];
#pragma unroll
    for (int m = 0; m < 2; m++)
#pragma unroll
        for (int r = 0; r < 4; r++) { lsum[m][r] = 0.f; vacc[m][r] = 0.f; }

    const bf* kbase = KL + ((size_t)b * NN) * ND + h * 32;
    for (int kt = 0; kt < 8; kt++) {
        const int k0 = kt * 128;
        __syncthreads();
#pragma unroll
        for (int i = 0; i < 2; i++) {
            int f = t + i * 256;
            int row = ((f >> 6) << 4) + (f & 15);
            int chunk = (f >> 4) & 3;
            *(bf16x8*)&Kf[f * 8] = *(const bf16x8*)(kbase + (size_t)(k0 + row) * ND + chunk * 8);
        }
        if (t < 128) vv[t] = value[(size_t)b * NN + k0 + t];
        __syncthreads();
#pragma unroll
        for (int s = 0; s < 8; s++) {
            bf16x8 bfr = *(const bf16x8*)&Kf[(s * 64 + lane) * 8];
            float vcol = vv[s * 16 + (lane & 15)];
#pragma unroll
            for (int m = 0; m < 2; m++) {
                f32x4 acc = {0.f, 0.f, 0.f, 0.f};
                acc = __builtin_amdgcn_mfma_f32_16x16x32_bf16(qf[m], bfr, acc, 0, 0, 0);
#pragma unroll
                for (int r = 0; r < 4; r++) {
                    float p;
                    asm("v_exp_f32 %0, %1\n\ts_nop 0" : "=v"(p) : "v"(acc[r]));
                    lsum[m][r] += p;
                    vacc[m][r] += p * vcol;
                }
            }
        }
    }
    // epilogue: whole from q.KG (linear in k: sum_l (q.k_l) v_l = q . KG)
    float kgf[8];
#pragma unroll
    for (int j = 0; j < 8; j++) kgf[j] = KG[(size_t)bh * 32 + (lane >> 4) * 8 + j];
    const float lam = lamda[0];
#pragma unroll
    for (int m = 0; m < 2; m++) {
        float dot = 0.f;
#pragma unroll
        for (int j = 0; j < 8; j++) {
            float qj = __uint_as_float(((unsigned int)(unsigned short)qf[m][j]) << 16);
            dot += qj * kgf[j];
        }
        dot += __shfl_xor(dot, 16, 64);
        dot += __shfl_xor(dot, 32, 64);   // lane l now holds full dot for row (l&15)
#pragma unroll
        for (int r = 0; r < 4; r++) {
            float ls = lsum[m][r], va = vacc[m][r];
#pragma unroll
            for (int off = 1; off < 16; off <<= 1) {
                ls += __shfl_xor(ls, off, 64);
                va += __shfl_xor(va, off, 64);
            }
            float dw = __shfl(dot, (lane >> 4) * 4 + r, 64);
            if ((lane & 15) == 0) {
                int q = q0 + m * 16 + (lane >> 4) * 4 + r;
                float part = va / ls;
                float whole = fmaxf(dw * (WHOLE_LN2 / 1024.0f), 0.f);
                float f = ((1.f - lam) * part + lam * whole) * 0.125f;
                atomicAdd(&out[((size_t)b * NN + q) * 8], f);
            }
        }
    }
}

// ---------------- pmms16_k: ONE phase-A stage; grid (16 chunks, 16 batches) x 1024 ----------------
// 64-row chunks, 16 lanes/row in the z-pass (all 1024 threads active); fused mu-reduce.
__global__ __launch_bounds__(1024) void pmms16_k(
    const float* __restrict__ query, const float* __restrict__ mu0a,
    const float* __restrict__ pin, float* __restrict__ pout, int stage)
{
    __shared__ float muT[5 * 256];      // [k][c]
    __shared__ float z_s[64][8];        // [n_local][k]
    __shared__ float red[32];
    __shared__ float red2[256 * 5 * 4]; // [c][k][rg]
    const int chunk = blockIdx.x, b = blockIdx.y;
    const int t = threadIdx.x;
    const int wave = t >> 6, lane = t & 63;

    // ---- mu for this stage (reduce NCH partials, colsum-normalize, l2-normalize) ----
    if (stage == 0) {
        for (int idx = t; idx < 1280; idx += 1024)
            muT[idx] = mu0a[(idx & 255) * 5 + (idx >> 8)];
        __syncthreads();
    } else {
        for (int idx = t; idx < 1280; idx += 1024) {
            int k = idx >> 8;
            float s = 0.f, cs = 0.f;
            for (int ch = 0; ch < NCH; ch++) {
                const float* pbch = pin + ((size_t)(b * NCH + ch)) * PSTRIDE;
                s  += pbch[idx];
                cs += pbch[1280 + k];
            }
            muT[idx] = s / (1e-6f + cs);
        }
        __syncthreads();
        if (t < 256) {
#pragma unroll
            for (int k = 0; k < 5; k++) {
                float v = muT[k * 256 + t];
                float s = wave_reduce_sum(v * v);
                if (lane == 0) red[wave * 5 + k] = s;
            }
        }
        __syncthreads();
        if (t < 5) red[20 + t] = 1.0f / (1e-6f + sqrtf(red[t] + red[5 + t] + red[10 + t] + red[15 + t]));
        __syncthreads();
        for (int idx = t; idx < 1280; idx += 1024)
            muT[idx] *= red[20 + (idx >> 8)];
        __syncthreads();
    }

    // ---- z-pass: 64 rows, 16 lanes/row (all threads active) ----
    {
        const int n_local = t >> 4, part = t & 15;
        const float* qrow = query + ((size_t)b * NN + chunk * 64 + n_local) * ND + part * 16;
        float lg[5] = {0,0,0,0,0};
#pragma unroll
        for (int c4 = 0; c4 < 16; c4 += 4) {
            float4 qv = *(const float4*)&qrow[c4];
#pragma unroll
            for (int k = 0; k < 5; k++) {
                float4 mv = *(const float4*)&muT[k * 256 + part * 16 + c4];
                lg[k] += qv.x*mv.x + qv.y*mv.y + qv.z*mv.z + qv.w*mv.w;
            }
        }
#pragma unroll
        for (int k = 0; k < 5; k++) {
            lg[k] += __shfl_xor(lg[k], 1, 64);
            lg[k] += __shfl_xor(lg[k], 2, 64);
            lg[k] += __shfl_xor(lg[k], 4, 64);
            lg[k] += __shfl_xor(lg[k], 8, 64);
        }
        float mx = lg[0];
#pragma unroll
        for (int k = 1; k < 5; k++) mx = fmaxf(mx, lg[k]);
        float e[5], ssum = 0.f;
#pragma unroll
        for (int k = 0; k < 5; k++) { e[k] = expf(20.0f * (lg[k] - mx)); ssum += e[k]; }
        float is = 1.0f / ssum;
        if (part == 0) {
#pragma unroll
            for (int k = 0; k < 5; k++) z_s[n_local][k] = e[k] * is;
        }
    }
    __syncthreads();

    // ---- col-pass: thread owns (c = t&255, rg = t>>8); 16 rows each ----
    {
        const int c = t & 255, rg = t >> 8;
        float pa[5] = {0,0,0,0,0};
        const float* qcol = query + ((size_t)b * NN + chunk * 64 + rg * 16) * ND + c;
#pragma unroll 4
        for (int nl = 0; nl < 16; nl++) {
            float qv = qcol[(size_t)nl * ND];
            float4 z4 = *(const float4*)&z_s[rg * 16 + nl][0];
            float z4v = z_s[rg * 16 + nl][4];
            pa[0] += qv * z4.x; pa[1] += qv * z4.y; pa[2] += qv * z4.z;
            pa[3] += qv * z4.w; pa[4] += qv * z4v;
        }
#pragma unroll
        for (int k = 0; k < 5; k++) red2[(c * 5 + k) * 4 + rg] = pa[k];
    }
    __syncthreads();

    float* pb = pout + ((size_t)(b * NCH + chunk)) * PSTRIDE;
    for (int idx = t; idx < 1280; idx += 1024) {
        int c = idx & 255, k = idx >> 8;
        const float* r4 = &red2[(c * 5 + k) * 4];
        pb[idx] = r4[0] + r4[1] + r4[2] + r4[3];
    }
    if (t < 5) {
        float s = 0.f;
#pragma unroll 8
        for (int nl = 0; nl < 64; nl++) s += z_s[nl][t];
        pb[1280 + t] = s;
    }
}

// ---------------- phase B: final reduce + 10 tiny stages, one 64-thread block per batch ----------------
__global__ __launch_bounds__(64) void pmms_b_k(
    const float* __restrict__ pin, const float* __restrict__ mu0b,
    float* __restrict__ m1_ws, float* __restrict__ mu2_ws)
{
    int b = blockIdx.x, lane = threadIdx.x;
    float nd[5][4];
    float cs[5] = {0,0,0,0,0};
#pragma unroll
    for (int n = 0; n < 5; n++)
#pragma unroll
        for (int j = 0; j < 4; j++) nd[n][j] = 0.f;
    for (int ch = 0; ch < NCH; ch++) {
        const float* pb = pin + ((size_t)(b * NCH + ch)) * PSTRIDE;
#pragma unroll
        for (int n = 0; n < 5; n++)
#pragma unroll
            for (int j = 0; j < 4; j++) nd[n][j] += pb[n * 256 + lane + 64 * j];
#pragma unroll
        for (int n = 0; n < 5; n++) cs[n] += pb[1280 + n];
    }
#pragma unroll
    for (int n = 0; n < 5; n++) {
        float inv = 1.0f / (1e-6f + cs[n]);
        float sq = 0.f;
#pragma unroll
        for (int j = 0; j < 4; j++) { nd[n][j] *= inv; sq += nd[n][j] * nd[n][j]; }
        float s = wave_allreduce_sum(sq);
        float nr = 1.0f / (1e-6f + sqrtf(s));
#pragma unroll
        for (int j = 0; j < 4; j++) {
            nd[n][j] *= nr;
            m1_ws[((size_t)b * 5 + n) * 256 + lane + 64 * j] = nd[n][j];
        }
    }
    float mu[2][4];
#pragma unroll
    for (int k = 0; k < 2; k++)
#pragma unroll
        for (int j = 0; j < 4; j++) mu[k][j] = mu0b[(lane + 64 * j) * 2 + k];
    for (int stage = 0; stage < 10; stage++) {
        float z[5][2];
        float colsum0 = 0.f, colsum1 = 0.f;
#pragma unroll
        for (int n = 0; n < 5; n++) {
            float l0 = 0.f, l1 = 0.f;
#pragma unroll
            for (int j = 0; j < 4; j++) { l0 += nd[n][j] * mu[0][j]; l1 += nd[n][j] * mu[1][j]; }
            l0 = wave_allreduce_sum(l0);
            l1 = wave_allreduce_sum(l1);
            float a0 = 20.0f * l0, a1 = 20.0f * l1;
            float mxv = fmaxf(a0, a1);
            float e0 = expf(a0 - mxv), e1 = expf(a1 - mxv);
            float inv = 1.0f / (e0 + e1);
            z[n][0] = e0 * inv; z[n][1] = e1 * inv;
            colsum0 += z[n][0]; colsum1 += z[n][1];
        }
        float i0 = 1.0f / (1e-6f + colsum0), i1 = 1.0f / (1e-6f + colsum1);
#pragma unroll
        for (int k = 0; k < 2; k++) {
            float iv = k ? i1 : i0;
            float sq = 0.f;
            float nm[4];
#pragma unroll
            for (int j = 0; j < 4; j++) {
                float v = 0.f;
#pragma unroll
                for (int n = 0; n < 5; n++) v += nd[n][j] * z[n][k];
                v *= iv;
                nm[j] = v; sq += v * v;
            }
            float s = wave_allreduce_sum(sq);
            float nr = 1.0f / (1e-6f + sqrtf(s));
#pragma unroll
            for (int j = 0; j < 4; j++) mu[k][j] = nm[j] * nr;
        }
    }
#pragma unroll
    for (int k = 0; k < 2; k++)
#pragma unroll
        for (int j = 0; j < 4; j++) mu2_ws[((size_t)b * 2 + k) * 256 + lane + 64 * j] = mu[k][j];
}

// ---------------- P1 = softmax(q.m1), P2 = softmax(q.mu2) ----------------
__global__ __launch_bounds__(256) void pmap_k(
    const float* __restrict__ query, const float* __restrict__ m1_ws,
    const float* __restrict__ mu2_ws, float* __restrict__ P1, float* __restrict__ P2)
{
    __shared__ float ms[7 * 256];
    int b = blockIdx.y;
    int t = threadIdx.x;
    int n = blockIdx.x * 256 + t;
    for (int idx = t; idx < 1280; idx += 256) ms[idx] = m1_ws[(size_t)b * 1280 + idx];
    for (int idx = t; idx < 512; idx += 256) ms[1280 + idx] = mu2_ws[(size_t)b * 512 + idx];
    __syncthreads();
    const float* qrow = query + ((size_t)b * NN + n) * ND;
    float lg[7] = {0,0,0,0,0,0,0};
    for (int c4 = 0; c4 < 256; c4 += 4) {
        float4 qv = *(const float4*)&qrow[c4];
#pragma unroll
        for (int k = 0; k < 7; k++) {
            float4 mv = *(const float4*)&ms[k * 256 + c4];
            lg[k] += qv.x*mv.x + qv.y*mv.y + qv.z*mv.z + qv.w*mv.w;
        }
    }
    float mx = lg[0];
#pragma unroll
    for (int k = 1; k < 5; k++) mx = fmaxf(mx, lg[k]);
    float e[5], ssum = 0.f;
#pragma unroll
    for (int k = 0; k < 5; k++) { e[k] = expf(lg[k] - mx); ssum += e[k]; }
    float is = 1.0f / ssum;
#pragma unroll
    for (int k = 0; k < 5; k++) P1[((size_t)b * 5 + k) * NN + n] = e[k] * is;
    float mx2 = fmaxf(lg[5], lg[6]);
    float e0 = expf(lg[5] - mx2), e1 = expf(lg[6] - mx2);
    float inv = 1.0f / (e0 + e1);
    P2[((size_t)b * 2 + 0) * NN + n] = e0 * inv;
    P2[((size_t)b * 2 + 1) * NN + n] = e1 * inv;
}

// ---------------- node_weight conv: one (b, ch) per block ----------------
__global__ __launch_bounds__(1024) void nwconv_k(
    const float* __restrict__ P1, const float* __restrict__ P2,
    const float* __restrict__ w1a, const float* __restrict__ b1a,
    const float* __restrict__ ga,  const float* __restrict__ bea,
    const float* __restrict__ w2a, const float* __restrict__ b2a,
    const float* __restrict__ w1b, const float* __restrict__ b1b,
    const float* __restrict__ gb,  const float* __restrict__ beb,
    const float* __restrict__ w2b, const float* __restrict__ b2b,
    float* __restrict__ out)
{
    __shared__ float img[34 * 34];
    __shared__ float mid[16][34 * 34];
    __shared__ float w1s[144], w2s[144], bs[16], gs[16], bes[16], b2s[1];
    int ch = blockIdx.x, b = blockIdx.y;
    int t = threadIdx.x;
    int i = t >> 5, j = t & 31;
    const float* xsrc = (ch < 5) ? &P1[((size_t)b * 5 + ch) * NN]
                                 : &P2[((size_t)b * 2 + (ch - 5)) * NN];
    if (t < 144) { w1s[t] = (ch < 5 ? w1a : w1b)[t]; w2s[t] = (ch < 5 ? w2a : w2b)[t]; }
    if (t >= 256 && t < 272) {
        int y = t - 256;
        bs[y] = (ch < 5 ? b1a : b1b)[y];
        gs[y] = (ch < 5 ? ga : gb)[y];
        bes[y] = (ch < 5 ? bea : beb)[y];
    }
    if (t == 512) b2s[0] = (ch < 5 ? b2a : b2b)[0];
    for (int idx = t; idx < 1156; idx += 1024) img[idx] = 0.f;
    for (int idx = t; idx < 16 * 1156; idx += 1024) ((float*)mid)[idx] = 0.f;
    __syncthreads();
    float xv = xsrc[t];
    img[(i + 1) * 34 + (j + 1)] = xv;
    __syncthreads();
    float r[9];
#pragma unroll
    for (int dy = 0; dy < 3; dy++)
#pragma unroll
        for (int dx = 0; dx < 3; dx++)
            r[dy * 3 + dx] = img[(i + dy) * 34 + (j + dx)];
    const float bninv = rsqrtf(1.0f + 1e-5f);
#pragma unroll
    for (int oc = 0; oc < 16; oc++) {
        float a = 0.f;
#pragma unroll
        for (int q2 = 0; q2 < 9; q2++) a += w1s[oc * 9 + q2] * r[q2];
        a += bs[oc];
        a = gs[oc] * (a * bninv) + bes[oc];
        a = fmaxf(a, 0.f);
        mid[oc][(i + 1) * 34 + (j + 1)] = a;
    }
    __syncthreads();
    float acc2 = b2s[0];
#pragma unroll
    for (int oc = 0; oc < 16; oc++)
#pragma unroll
        for (int dy = 0; dy < 3; dy++)
#pragma unroll
            for (int dx = 0; dx < 3; dx++)
                acc2 += w2s[oc * 9 + dy * 3 + dx] * mid[oc][(i + dy) * 34 + (j + dx)];
    float sig = 1.0f / (1.0f + expf(-acc2));
    out[((size_t)(b * NN + t)) * 8 + 1 + ch] = xv * sig;
}

extern "C" void kernel_launch(void* const* d_in, const int* in_sizes, int n_in,
                              void* d_out, int out_size, void* d_ws, size_t ws_size,
                              hipStream_t stream) {
    const float* query = (const float*)d_in[0];
    const float* key   = (const float*)d_in[1];
    const float* value = (const float*)d_in[2];
    const float* lamda = (const float*)d_in[3];
    const float* W0 = (const float*)d_in[4];
    const float* b0 = (const float*)d_in[5];
    const float* W1 = (const float*)d_in[6];
    const float* b1 = (const float*)d_in[7];
    const float* mu_a = (const float*)d_in[8];
    const float* mu_b = (const float*)d_in[9];
    const float* nw1_w1 = (const float*)d_in[10];
    const float* nw1_b1 = (const float*)d_in[11];
    const float* nw1_g  = (const float*)d_in[12];
    const float* nw1_be = (const float*)d_in[13];
    const float* nw1_w2 = (const float*)d_in[14];
    const float* nw1_b2 = (const float*)d_in[15];
    const float* nw2_w1 = (const float*)d_in[16];
    const float* nw2_b1 = (const float*)d_in[17];
    const float* nw2_g  = (const float*)d_in[18];
    const float* nw2_be = (const float*)d_in[19];
    const float* nw2_w2 = (const float*)d_in[20];
    const float* nw2_b2 = (const float*)d_in[21];
    float* out = (float*)d_out;

    // ws: QLb [0,8MB) + KLb [8,16MB) as bf16 (attention path).
    bf* QLb = (bf*)d_ws;
    bf* KLb = (bf*)((char*)d_ws + ((size_t)8 << 20));
    // PMMS scratch (~3.5 MB) OVERLAYS the QLb region. Safe: attn5_k (last consumer of
    // QLb/KLb) completes before the first pmms16_k on the serialized stream.
    float* PA   = (float*)d_ws;
    float* PB   = PA + (size_t)16 * NCH * PSTRIDE;
    float* m1w  = PB + (size_t)16 * NCH * PSTRIDE;
    float* mu2w = m1w + (size_t)16 * 1280;
    float* P1w  = mu2w + (size_t)16 * 512;
    float* P2w  = P1w + (size_t)16 * 5 * 1024;
    // Outside the 16MB QL/KL span: KG (16KB) — NOT overlaid.
    float* KGw = (float*)((char*)d_ws + ((size_t)16 << 20));

    gemm2_k<<<dim3(256, 1, 2), 256, 0, stream>>>(query, key, W0, b0, W1, b1, QLb, KLb);
    kg_k<<<128, 256, 0, stream>>>(KLb, value, KGw, out);   // also zeroes out ch0
    attn5_k<<<dim3(128, 8), 256, 0, stream>>>(QLb, KLb, value, lamda, KGw, out);

    // stage 0: mu0a -> PA; stages 1..9 ping-pong (9 odd -> output PB)
    pmms16_k<<<dim3(NCH, 16), 1024, 0, stream>>>(query, mu_a, PA, PA, 0);
    for (int s = 1; s < 10; s++) {
        const float* pin = (s & 1) ? PA : PB;
        float* pout      = (s & 1) ? PB : PA;
        pmms16_k<<<dim3(NCH, 16), 1024, 0, stream>>>(query, mu_a, pin, pout, s);
    }
    pmms_b_k<<<16, 64, 0, stream>>>(PB, mu_b, m1w, mu2w);
    pmap_k<<<dim3(4, 16), 256, 0, stream>>>(query, m1w, mu2w, P1w, P2w);
    nwconv_k<<<dim3(7, 16), 1024, 0, stream>>>(P1w, P2w,
                                    nw1_w1, nw1_b1, nw1_g, nw1_be, nw1_w2, nw1_b2,
                                    nw2_w1, nw2_b1, nw2_g, nw2_be, nw2_w2, nw2_b2, out);
}

// Round 11
// 335.864 us; speedup vs baseline: 5.5641x; 1.0173x over previous
//
#include <hip/hip_runtime.h>
#include <hip/hip_bf16.h>
#include <math.h>

#define NN 1024
#define ND 256
#define NCH 16        // chunks per batch in phase A (64 rows per chunk)
#define PSTRIDE 1288  // per-(b,chunk) partial block: 5*256 mu-acc + 5 colsum + pad

typedef __hip_bfloat16 bf;
__device__ __forceinline__ float bf2f(bf h) { return __bfloat162float(h); }

typedef __attribute__((ext_vector_type(8))) short bf16x8;
typedef __attribute__((ext_vector_type(4))) float f32x4;

// alpha = (1/sqrt(32)) * log2(e); folded into QL so attn uses v_exp (2^x) directly.
#define QL_ALPHA 0.25503486216f
#define WHOLE_LN2 0.6931471805599453f

__device__ __forceinline__ float wave_reduce_sum(float v) {
#pragma unroll
    for (int off = 32; off > 0; off >>= 1) v += __shfl_down(v, off, 64);
    return v;
}

// ---------------- split-bf16 MFMA GEMM: QL = alpha*(query@W0^T+b0) ; KL = key@W1^T+b1 ----------------
__global__ __launch_bounds__(256) void gemm2_k(
    const float* __restrict__ Aq, const float* __restrict__ Ak,
    const float* __restrict__ W0, const float* __restrict__ b0v,
    const float* __restrict__ W1, const float* __restrict__ b1v,
    bf* __restrict__ QL, bf* __restrict__ KL)
{
    const float* A; const float* Bw; const float* bias; bf* C; float alpha;
    if (blockIdx.z == 0) { A = Aq; Bw = W0; bias = b0v; C = QL; alpha = QL_ALPHA; }
    else                 { A = Ak; Bw = W1; bias = b1v; C = KL; alpha = 1.0f; }
    __shared__ short Ahi[4 * 64 * 8],  Alo[4 * 64 * 8];
    __shared__ short Bhi[16 * 64 * 8], Blo[16 * 64 * 8];
    const int t = threadIdx.x;
    const int wave = t >> 6, lane = t & 63;
    const int m0 = blockIdx.x * 64;

    f32x4 acc[4][4];
#pragma unroll
    for (int m = 0; m < 4; m++)
#pragma unroll
        for (int n = 0; n < 4; n++)
#pragma unroll
            for (int r = 0; r < 4; r++) acc[m][n][r] = 0.f;

    for (int k0 = 0; k0 < 256; k0 += 32) {
        __syncthreads();
        {
            int fm = t >> 6, ls = t & 63;
            const float* src = A + (size_t)(m0 + fm * 16 + (ls & 15)) * 256 + k0 + ((ls >> 4) * 8);
            float4 x = *(const float4*)src;
            float4 y = *(const float4*)(src + 4);
            float v[8] = {x.x, x.y, x.z, x.w, y.x, y.y, y.z, y.w};
            short h[8], l8[8];
#pragma unroll
            for (int j = 0; j < 8; j++) {
                bf hb = __float2bfloat16(v[j]);
                float hf = __bfloat162float(hb);
                bf lb = __float2bfloat16(v[j] - hf);
                h[j] = *(short*)&hb; l8[j] = *(short*)&lb;
            }
            *(bf16x8*)&Ahi[t * 8] = *(bf16x8*)h;
            *(bf16x8*)&Alo[t * 8] = *(bf16x8*)l8;
        }
#pragma unroll
        for (int i = 0; i < 4; i++) {
            int idx = t + i * 256;
            int nf = idx >> 6, ls = idx & 63;
            const float* src = Bw + (size_t)(nf * 16 + (ls & 15)) * 256 + k0 + ((ls >> 4) * 8);
            float4 x = *(const float4*)src;
            float4 y = *(const float4*)(src + 4);
            float v[8] = {x.x, x.y, x.z, x.w, y.x, y.y, y.z, y.w};
            short h[8], l8[8];
#pragma unroll
            for (int j = 0; j < 8; j++) {
                bf hb = __float2bfloat16(v[j]);
                float hf = __bfloat162float(hb);
                bf lb = __float2bfloat16(v[j] - hf);
                h[j] = *(short*)&hb; l8[j] = *(short*)&lb;
            }
            *(bf16x8*)&Bhi[idx * 8] = *(bf16x8*)h;
            *(bf16x8*)&Blo[idx * 8] = *(bf16x8*)l8;
        }
        __syncthreads();
        bf16x8 ah[4], al[4], bh[4], bl[4];
#pragma unroll
        for (int m = 0; m < 4; m++) {
            ah[m] = *(const bf16x8*)&Ahi[(m * 64 + lane) * 8];
            al[m] = *(const bf16x8*)&Alo[(m * 64 + lane) * 8];
        }
#pragma unroll
        for (int n = 0; n < 4; n++) {
            int nf = wave * 4 + n;
            bh[n] = *(const bf16x8*)&Bhi[(nf * 64 + lane) * 8];
            bl[n] = *(const bf16x8*)&Blo[(nf * 64 + lane) * 8];
        }
#pragma unroll
        for (int m = 0; m < 4; m++)
#pragma unroll
            for (int n = 0; n < 4; n++) {
                acc[m][n] = __builtin_amdgcn_mfma_f32_16x16x32_bf16(ah[m], bh[n], acc[m][n], 0, 0, 0);
                acc[m][n] = __builtin_amdgcn_mfma_f32_16x16x32_bf16(ah[m], bl[n], acc[m][n], 0, 0, 0);
                acc[m][n] = __builtin_amdgcn_mfma_f32_16x16x32_bf16(al[m], bh[n], acc[m][n], 0, 0, 0);
            }
    }
#pragma unroll
    for (int n = 0; n < 4; n++) {
        int col = (wave * 4 + n) * 16 + (lane & 15);
        float bv = bias[col];
#pragma unroll
        for (int m = 0; m < 4; m++) {
            int row = m0 + m * 16 + (lane >> 4) * 4;
#pragma unroll
            for (int r = 0; r < 4; r++) {
                bf hv = __float2bfloat16((acc[m][n][r] + bv) * alpha);
                C[(size_t)(row + r) * 256 + col] = hv;
            }
        }
    }
}

// ---------------- KG[b][h][c] = sum_l KL[b,l,h*32+c] * value[b,l]; also zeroes out ch0 ----------------
__global__ __launch_bounds__(256) void kg_k(
    const bf* __restrict__ KL, const float* __restrict__ value, float* __restrict__ KG,
    float* __restrict__ out)
{
    const int bh = blockIdx.x, b = bh >> 3, h = bh & 7;
    const int t = threadIdx.x;
    // zero out channel 0 (rows h*128..h*128+127 of batch b) — exact 1:1 cover over grid
    if (t < 128) out[((size_t)b * NN + h * 128 + t) * 8] = 0.f;
    const int c = t & 31, rg = t >> 5;   // 8 row-groups of 128 rows
    float acc = 0.f;
    const bf* kp = KL + (size_t)b * NN * ND + h * 32 + c;
    const float* vp = value + (size_t)b * NN;
#pragma unroll 8
    for (int r = rg * 128; r < rg * 128 + 128; r++)
        acc += bf2f(kp[(size_t)r * ND]) * vp[r];
    __shared__ float kgs[8][33];
    kgs[rg][c] = acc;
    __syncthreads();
    if (t < 32) {
        float s = 0.f;
#pragma unroll
        for (int g = 0; g < 8; g++) s += kgs[g][t];
        KG[(size_t)bh * 32 + t] = s;
    }
}

// ---------------- MFMA flash attention: 32 q-rows/wave (grid 128x8 -> 4 waves/SIMD),
//                  v_exp inner, KG-based whole ----------------
__global__ __launch_bounds__(256) void attn5_k(
    const bf* __restrict__ QL, const bf* __restrict__ KL,
    const float* __restrict__ value, const float* __restrict__ lamda,
    const float* __restrict__ KG, float* __restrict__ out)
{
    const int bh = blockIdx.x; const int b = bh >> 3, h = bh & 7;
    const int t = threadIdx.x;
    const int wave = t >> 6, lane = t & 63;
    const int q0 = blockIdx.y * 128 + wave * 32;

    __shared__ bf Kf[128 * 32];   // 512 fragments * 8 bf16, fragment order
    __shared__ float vv[128];

    bf16x8 qf[2];
    {
        const bf* qbase = QL + ((size_t)b * NN) * ND + h * 32 + (lane >> 4) * 8;
#pragma unroll
        for (int m = 0; m < 2; m++)
            qf[m] = *(const bf16x8*)(qbase + (size_t)(q0 + m * 16 + (lane & 15)) * ND);
    }
    f32x4 lsum[2], vacc[2];
#pragma unroll
    for (int m = 0; m < 2; m++)
#pragma unroll
        for (int r = 0; r < 4; r++) { lsum[m][r] = 0.f; vacc[m][r] = 0.f; }

    const bf* kbase = KL + ((size_t)b * NN) * ND + h * 32;
    for (int kt = 0; kt < 8; kt++) {
        const int k0 = kt * 128;
        __syncthreads();
#pragma unroll
        for (int i = 0; i < 2; i++) {
            int f = t + i * 256;
            int row = ((f >> 6) << 4) + (f & 15);
            int chunk = (f >> 4) & 3;
            *(bf16x8*)&Kf[f * 8] = *(const bf16x8*)(kbase + (size_t)(k0 + row) * ND + chunk * 8);
        }
        if (t < 128) vv[t] = value[(size_t)b * NN + k0 + t];
        __syncthreads();
#pragma unroll
        for (int s = 0; s < 8; s++) {
            bf16x8 bfr = *(const bf16x8*)&Kf[(s * 64 + lane) * 8];
            float vcol = vv[s * 16 + (lane & 15)];
#pragma unroll
            for (int m = 0; m < 2; m++) {
                f32x4 acc = {0.f, 0.f, 0.f, 0.f};
                acc = __builtin_amdgcn_mfma_f32_16x16x32_bf16(qf[m], bfr, acc, 0, 0, 0);
#pragma unroll
                for (int r = 0; r < 4; r++) {
                    float p;
                    asm("v_exp_f32 %0, %1\n\ts_nop 0" : "=v"(p) : "v"(acc[r]));
                    lsum[m][r] += p;
                    vacc[m][r] += p * vcol;
                }
            }
        }
    }
    // epilogue: whole from q.KG (linear in k: sum_l (q.k_l) v_l = q . KG)
    float kgf[8];
#pragma unroll
    for (int j = 0; j < 8; j++) kgf[j] = KG[(size_t)bh * 32 + (lane >> 4) * 8 + j];
    const float lam = lamda[0];
#pragma unroll
    for (int m = 0; m < 2; m++) {
        float dot = 0.f;
#pragma unroll
        for (int j = 0; j < 8; j++) {
            float qj = __uint_as_float(((unsigned int)(unsigned short)qf[m][j]) << 16);
            dot += qj * kgf[j];
        }
        dot += __shfl_xor(dot, 16, 64);
        dot += __shfl_xor(dot, 32, 64);   // lane l now holds full dot for row (l&15)
#pragma unroll
        for (int r = 0; r < 4; r++) {
            float ls = lsum[m][r], va = vacc[m][r];
#pragma unroll
            for (int off = 1; off < 16; off <<= 1) {
                ls += __shfl_xor(ls, off, 64);
                va += __shfl_xor(va, off, 64);
            }
            float dw = __shfl(dot, (lane >> 4) * 4 + r, 64);
            if ((lane & 15) == 0) {
                int q = q0 + m * 16 + (lane >> 4) * 4 + r;
                float part = va / ls;
                float whole = fmaxf(dw * (WHOLE_LN2 / 1024.0f), 0.f);
                float f = ((1.f - lam) * part + lam * whole) * 0.125f;
                atomicAdd(&out[((size_t)b * NN + q) * 8], f);
            }
        }
    }
}

// ---------------- pmms16_k: ONE phase-A stage; grid (16 chunks, 16 batches) x 1024 ----------------
// 64-row chunks, 16 lanes/row in the z-pass (all 1024 threads active); fused mu-reduce.
__global__ __launch_bounds__(1024) void pmms16_k(
    const float* __restrict__ query, const float* __restrict__ mu0a,
    const float* __restrict__ pin, float* __restrict__ pout, int stage)
{
    __shared__ float muT[5 * 256];      // [k][c]
    __shared__ float z_s[64][8];        // [n_local][k]
    __shared__ float red[32];
    __shared__ float red2[256 * 5 * 4]; // [c][k][rg]
    const int chunk = blockIdx.x, b = blockIdx.y;
    const int t = threadIdx.x;
    const int wave = t >> 6, lane = t & 63;

    // ---- mu for this stage (reduce NCH partials, colsum-normalize, l2-normalize) ----
    if (stage == 0) {
        for (int idx = t; idx < 1280; idx += 1024)
            muT[idx] = mu0a[(idx & 255) * 5 + (idx >> 8)];
        __syncthreads();
    } else {
        for (int idx = t; idx < 1280; idx += 1024) {
            int k = idx >> 8;
            float s = 0.f, cs = 0.f;
            for (int ch = 0; ch < NCH; ch++) {
                const float* pbch = pin + ((size_t)(b * NCH + ch)) * PSTRIDE;
                s  += pbch[idx];
                cs += pbch[1280 + k];
            }
            muT[idx] = s / (1e-6f + cs);
        }
        __syncthreads();
        if (t < 256) {
#pragma unroll
            for (int k = 0; k < 5; k++) {
                float v = muT[k * 256 + t];
                float s = wave_reduce_sum(v * v);
                if (lane == 0) red[wave * 5 + k] = s;
            }
        }
        __syncthreads();
        if (t < 5) red[20 + t] = 1.0f / (1e-6f + sqrtf(red[t] + red[5 + t] + red[10 + t] + red[15 + t]));
        __syncthreads();
        for (int idx = t; idx < 1280; idx += 1024)
            muT[idx] *= red[20 + (idx >> 8)];
        __syncthreads();
    }

    // ---- z-pass: 64 rows, 16 lanes/row (all threads active) ----
    {
        const int n_local = t >> 4, part = t & 15;
        const float* qrow = query + ((size_t)b * NN + chunk * 64 + n_local) * ND + part * 16;
        float lg[5] = {0,0,0,0,0};
#pragma unroll
        for (int c4 = 0; c4 < 16; c4 += 4) {
            float4 qv = *(const float4*)&qrow[c4];
#pragma unroll
            for (int k = 0; k < 5; k++) {
                float4 mv = *(const float4*)&muT[k * 256 + part * 16 + c4];
                lg[k] += qv.x*mv.x + qv.y*mv.y + qv.z*mv.z + qv.w*mv.w;
            }
        }
#pragma unroll
        for (int k = 0; k < 5; k++) {
            lg[k] += __shfl_xor(lg[k], 1, 64);
            lg[k] += __shfl_xor(lg[k], 2, 64);
            lg[k] += __shfl_xor(lg[k], 4, 64);
            lg[k] += __shfl_xor(lg[k], 8, 64);
        }
        float mx = lg[0];
#pragma unroll
        for (int k = 1; k < 5; k++) mx = fmaxf(mx, lg[k]);
        float e[5], ssum = 0.f;
#pragma unroll
        for (int k = 0; k < 5; k++) { e[k] = expf(20.0f * (lg[k] - mx)); ssum += e[k]; }
        float is = 1.0f / ssum;
        if (part == 0) {
#pragma unroll
            for (int k = 0; k < 5; k++) z_s[n_local][k] = e[k] * is;
        }
    }
    __syncthreads();

    // ---- col-pass: thread owns (c = t&255, rg = t>>8); 16 rows each ----
    {
        const int c = t & 255, rg = t >> 8;
        float pa[5] = {0,0,0,0,0};
        const float* qcol = query + ((size_t)b * NN + chunk * 64 + rg * 16) * ND + c;
#pragma unroll 4
        for (int nl = 0; nl < 16; nl++) {
            float qv = qcol[(size_t)nl * ND];
            float4 z4 = *(const float4*)&z_s[rg * 16 + nl][0];
            float z4v = z_s[rg * 16 + nl][4];
            pa[0] += qv * z4.x; pa[1] += qv * z4.y; pa[2] += qv * z4.z;
            pa[3] += qv * z4.w; pa[4] += qv * z4v;
        }
#pragma unroll
        for (int k = 0; k < 5; k++) red2[(c * 5 + k) * 4 + rg] = pa[k];
    }
    __syncthreads();

    float* pb = pout + ((size_t)(b * NCH + chunk)) * PSTRIDE;
    for (int idx = t; idx < 1280; idx += 1024) {
        int c = idx & 255, k = idx >> 8;
        const float* r4 = &red2[(c * 5 + k) * 4];
        pb[idx] = r4[0] + r4[1] + r4[2] + r4[3];
    }
    if (t < 5) {
        float s = 0.f;
#pragma unroll 8
        for (int nl = 0; nl < 64; nl++) s += z_s[nl][t];
        pb[1280 + t] = s;
    }
}

// ---------------- phase B v2: 256 threads (4 waves), one CHANNEL per thread ----------------
// Cross-channel reductions = per-wave butterflies with ILP (10 independent) + 40-float
// LDS combine; softmax recomputed redundantly by every thread (no serialization).
// Two LDS buffers -> exactly 2 barriers per stage.
__global__ __launch_bounds__(256) void pmms_b2_k(
    const float* __restrict__ pin, const float* __restrict__ mu0b,
    float* __restrict__ m1_ws, float* __restrict__ mu2_ws)
{
    __shared__ float wredA[4 * 10];   // [wave][dot 0..9]
    __shared__ float wredB[4 * 10];   // [wave][norm 0..1] (+slack)
    const int b = blockIdx.x, t = threadIdx.x;
    const int wave = t >> 6, lane = t & 63;
    const int c = t;   // channel 0..255

    // ---- reduce 16 chunk partials -> per-channel nd[5]; colsum-normalize ----
    float nd[5] = {0,0,0,0,0};
    float cs[5] = {0,0,0,0,0};
    for (int ch = 0; ch < NCH; ch++) {
        const float* pb = pin + ((size_t)(b * NCH + ch)) * PSTRIDE;
#pragma unroll
        for (int n = 0; n < 5; n++) nd[n] += pb[n * 256 + c];
#pragma unroll
        for (int n = 0; n < 5; n++) cs[n] += pb[1280 + n];
    }
#pragma unroll
    for (int n = 0; n < 5; n++) nd[n] *= 1.0f / (1e-6f + cs[n]);

    // ---- l2-normalize m1 over channels (butterfly + cross-wave via wredB) ----
    {
        float sq[5];
#pragma unroll
        for (int n = 0; n < 5; n++) {
            sq[n] = nd[n] * nd[n];
#pragma unroll
            for (int off = 1; off < 64; off <<= 1) sq[n] += __shfl_xor(sq[n], off, 64);
        }
        if (lane == 0) {
#pragma unroll
            for (int n = 0; n < 5; n++) wredB[wave * 10 + n] = sq[n];
        }
        __syncthreads();
#pragma unroll
        for (int n = 0; n < 5; n++) {
            float s = wredB[n] + wredB[10 + n] + wredB[20 + n] + wredB[30 + n];
            nd[n] *= 1.0f / (1e-6f + sqrtf(s));
            m1_ws[(size_t)b * 1280 + n * 256 + c] = nd[n];
        }
    }

    float mu0 = mu0b[c * 2 + 0], mu1 = mu0b[c * 2 + 1];
    for (int stage = 0; stage < 10; stage++) {
        // 10 independent per-channel products -> per-wave butterflies (ILP) -> wredA
        float p[10];
#pragma unroll
        for (int n = 0; n < 5; n++) { p[n * 2] = nd[n] * mu0; p[n * 2 + 1] = nd[n] * mu1; }
#pragma unroll
        for (int i = 0; i < 10; i++) {
#pragma unroll
            for (int off = 1; off < 64; off <<= 1) p[i] += __shfl_xor(p[i], off, 64);
        }
        if (lane == 0) {
#pragma unroll
            for (int i = 0; i < 10; i++) wredA[wave * 10 + i] = p[i];
        }
        __syncthreads();
        // every thread redundantly: full dots, softmax over k, colsum-normalize
        float z[10];
        float cs0 = 0.f, cs1 = 0.f;
#pragma unroll
        for (int n = 0; n < 5; n++) {
            float a0 = 20.0f * (wredA[n*2]   + wredA[10 + n*2]   + wredA[20 + n*2]   + wredA[30 + n*2]);
            float a1 = 20.0f * (wredA[n*2+1] + wredA[10 + n*2+1] + wredA[20 + n*2+1] + wredA[30 + n*2+1]);
            float mx = fmaxf(a0, a1);
            float e0 = expf(a0 - mx), e1 = expf(a1 - mx);
            float inv = 1.0f / (e0 + e1);
            z[n*2] = e0 * inv; z[n*2+1] = e1 * inv;
            cs0 += z[n*2]; cs1 += z[n*2+1];
        }
        float i0 = 1.0f / (1e-6f + cs0), i1 = 1.0f / (1e-6f + cs1);
        float nm0 = 0.f, nm1 = 0.f;
#pragma unroll
        for (int n = 0; n < 5; n++) { nm0 += nd[n] * z[n*2]; nm1 += nd[n] * z[n*2+1]; }
        nm0 *= i0; nm1 *= i1;
        // l2-norm of new mu over channels -> wredB
        float s0 = nm0 * nm0, s1 = nm1 * nm1;
#pragma unroll
        for (int off = 1; off < 64; off <<= 1) {
            s0 += __shfl_xor(s0, off, 64);
            s1 += __shfl_xor(s1, off, 64);
        }
        if (lane == 0) { wredB[wave * 10 + 0] = s0; wredB[wave * 10 + 1] = s1; }
        __syncthreads();
        float t0 = wredB[0] + wredB[10] + wredB[20] + wredB[30];
        float t1 = wredB[1] + wredB[11] + wredB[21] + wredB[31];
        mu0 = nm0 * (1.0f / (1e-6f + sqrtf(t0)));
        mu1 = nm1 * (1.0f / (1e-6f + sqrtf(t1)));
        // next stage's wredA writes are after its own barrier-free butterfly but
        // all wredA READS happened before this stage's second barrier -> safe.
    }
    mu2_ws[((size_t)b * 2 + 0) * 256 + c] = mu0;
    mu2_ws[((size_t)b * 2 + 1) * 256 + c] = mu1;
}

// ---------------- P1 = softmax(q.m1), P2 = softmax(q.mu2) ----------------
__global__ __launch_bounds__(256) void pmap_k(
    const float* __restrict__ query, const float* __restrict__ m1_ws,
    const float* __restrict__ mu2_ws, float* __restrict__ P1, float* __restrict__ P2)
{
    __shared__ float ms[7 * 256];
    int b = blockIdx.y;
    int t = threadIdx.x;
    int n = blockIdx.x * 256 + t;
    for (int idx = t; idx < 1280; idx += 256) ms[idx] = m1_ws[(size_t)b * 1280 + idx];
    for (int idx = t; idx < 512; idx += 256) ms[1280 + idx] = mu2_ws[(size_t)b * 512 + idx];
    __syncthreads();
    const float* qrow = query + ((size_t)b * NN + n) * ND;
    float lg[7] = {0,0,0,0,0,0,0};
    for (int c4 = 0; c4 < 256; c4 += 4) {
        float4 qv = *(const float4*)&qrow[c4];
#pragma unroll
        for (int k = 0; k < 7; k++) {
            float4 mv = *(const float4*)&ms[k * 256 + c4];
            lg[k] += qv.x*mv.x + qv.y*mv.y + qv.z*mv.z + qv.w*mv.w;
        }
    }
    float mx = lg[0];
#pragma unroll
    for (int k = 1; k < 5; k++) mx = fmaxf(mx, lg[k]);
    float e[5], ssum = 0.f;
#pragma unroll
    for (int k = 0; k < 5; k++) { e[k] = expf(lg[k] - mx); ssum += e[k]; }
    float is = 1.0f / ssum;
#pragma unroll
    for (int k = 0; k < 5; k++) P1[((size_t)b * 5 + k) * NN + n] = e[k] * is;
    float mx2 = fmaxf(lg[5], lg[6]);
    float e0 = expf(lg[5] - mx2), e1 = expf(lg[6] - mx2);
    float inv = 1.0f / (e0 + e1);
    P2[((size_t)b * 2 + 0) * NN + n] = e0 * inv;
    P2[((size_t)b * 2 + 1) * NN + n] = e1 * inv;
}

// ---------------- node_weight conv: one (b, ch) per block ----------------
__global__ __launch_bounds__(1024) void nwconv_k(
    const float* __restrict__ P1, const float* __restrict__ P2,
    const float* __restrict__ w1a, const float* __restrict__ b1a,
    const float* __restrict__ ga,  const float* __restrict__ bea,
    const float* __restrict__ w2a, const float* __restrict__ b2a,
    const float* __restrict__ w1b, const float* __restrict__ b1b,
    const float* __restrict__ gb,  const float* __restrict__ beb,
    const float* __restrict__ w2b, const float* __restrict__ b2b,
    float* __restrict__ out)
{
    __shared__ float img[34 * 34];
    __shared__ float mid[16][34 * 34];
    __shared__ float w1s[144], w2s[144], bs[16], gs[16], bes[16], b2s[1];
    int ch = blockIdx.x, b = blockIdx.y;
    int t = threadIdx.x;
    int i = t >> 5, j = t & 31;
    const float* xsrc = (ch < 5) ? &P1[((size_t)b * 5 + ch) * NN]
                                 : &P2[((size_t)b * 2 + (ch - 5)) * NN];
    if (t < 144) { w1s[t] = (ch < 5 ? w1a : w1b)[t]; w2s[t] = (ch < 5 ? w2a : w2b)[t]; }
    if (t >= 256 && t < 272) {
        int y = t - 256;
        bs[y] = (ch < 5 ? b1a : b1b)[y];
        gs[y] = (ch < 5 ? ga : gb)[y];
        bes[y] = (ch < 5 ? bea : beb)[y];
    }
    if (t == 512) b2s[0] = (ch < 5 ? b2a : b2b)[0];
    for (int idx = t; idx < 1156; idx += 1024) img[idx] = 0.f;
    for (int idx = t; idx < 16 * 1156; idx += 1024) ((float*)mid)[idx] = 0.f;
    __syncthreads();
    float xv = xsrc[t];
    img[(i + 1) * 34 + (j + 1)] = xv;
    __syncthreads();
    float r[9];
#pragma unroll
    for (int dy = 0; dy < 3; dy++)
#pragma unroll
        for (int dx = 0; dx < 3; dx++)
            r[dy * 3 + dx] = img[(i + dy) * 34 + (j + dx)];
    const float bninv = rsqrtf(1.0f + 1e-5f);
#pragma unroll
    for (int oc = 0; oc < 16; oc++) {
        float a = 0.f;
#pragma unroll
        for (int q2 = 0; q2 < 9; q2++) a += w1s[oc * 9 + q2] * r[q2];
        a += bs[oc];
        a = gs[oc] * (a * bninv) + bes[oc];
        a = fmaxf(a, 0.f);
        mid[oc][(i + 1) * 34 + (j + 1)] = a;
    }
    __syncthreads();
    float acc2 = b2s[0];
#pragma unroll
    for (int oc = 0; oc < 16; oc++)
#pragma unroll
        for (int dy = 0; dy < 3; dy++)
#pragma unroll
            for (int dx = 0; dx < 3; dx++)
                acc2 += w2s[oc * 9 + dy * 3 + dx] * mid[oc][(i + dy) * 34 + (j + dx)];
    float sig = 1.0f / (1.0f + expf(-acc2));
    out[((size_t)(b * NN + t)) * 8 + 1 + ch] = xv * sig;
}

extern "C" void kernel_launch(void* const* d_in, const int* in_sizes, int n_in,
                              void* d_out, int out_size, void* d_ws, size_t ws_size,
                              hipStream_t stream) {
    const float* query = (const float*)d_in[0];
    const float* key   = (const float*)d_in[1];
    const float* value = (const float*)d_in[2];
    const float* lamda = (const float*)d_in[3];
    const float* W0 = (const float*)d_in[4];
    const float* b0 = (const float*)d_in[5];
    const float* W1 = (const float*)d_in[6];
    const float* b1 = (const float*)d_in[7];
    const float* mu_a = (const float*)d_in[8];
    const float* mu_b = (const float*)d_in[9];
    const float* nw1_w1 = (const float*)d_in[10];
    const float* nw1_b1 = (const float*)d_in[11];
    const float* nw1_g  = (const float*)d_in[12];
    const float* nw1_be = (const float*)d_in[13];
    const float* nw1_w2 = (const float*)d_in[14];
    const float* nw1_b2 = (const float*)d_in[15];
    const float* nw2_w1 = (const float*)d_in[16];
    const float* nw2_b1 = (const float*)d_in[17];
    const float* nw2_g  = (const float*)d_in[18];
    const float* nw2_be = (const float*)d_in[19];
    const float* nw2_w2 = (const float*)d_in[20];
    const float* nw2_b2 = (const float*)d_in[21];
    float* out = (float*)d_out;

    // ws: QLb [0,8MB) + KLb [8,16MB) as bf16 (attention path).
    bf* QLb = (bf*)d_ws;
    bf* KLb = (bf*)((char*)d_ws + ((size_t)8 << 20));
    // PMMS scratch (~3.5 MB) OVERLAYS the QLb region. Safe: attn5_k (last consumer of
    // QLb/KLb) completes before the first pmms16_k on the serialized stream.
    float* PA   = (float*)d_ws;
    float* PB   = PA + (size_t)16 * NCH * PSTRIDE;
    float* m1w  = PB + (size_t)16 * NCH * PSTRIDE;
    float* mu2w = m1w + (size_t)16 * 1280;
    float* P1w  = mu2w + (size_t)16 * 512;
    float* P2w  = P1w + (size_t)16 * 5 * 1024;
    // Outside the 16MB QL/KL span: KG (16KB) — NOT overlaid.
    float* KGw = (float*)((char*)d_ws + ((size_t)16 << 20));

    gemm2_k<<<dim3(256, 1, 2), 256, 0, stream>>>(query, key, W0, b0, W1, b1, QLb, KLb);
    kg_k<<<128, 256, 0, stream>>>(KLb, value, KGw, out);   // also zeroes out ch0
    attn5_k<<<dim3(128, 8), 256, 0, stream>>>(QLb, KLb, value, lamda, KGw, out);

    // stage 0: mu0a -> PA; stages 1..9 ping-pong (9 odd -> output PB)
    pmms16_k<<<dim3(NCH, 16), 1024, 0, stream>>>(query, mu_a, PA, PA, 0);
    for (int s = 1; s < 10; s++) {
        const float* pin = (s & 1) ? PA : PB;
        float* pout      = (s & 1) ? PB : PA;
        pmms16_k<<<dim3(NCH, 16), 1024, 0, stream>>>(query, mu_a, pin, pout, s);
    }
    pmms_b2_k<<<16, 256, 0, stream>>>(PB, mu_b, m1w, mu2w);
    pmap_k<<<dim3(4, 16), 256, 0, stream>>>(query, m1w, mu2w, P1w, P2w);
    nwconv_k<<<dim3(7, 16), 1024, 0, stream>>>(P1w, P2w,
                                    nw1_w1, nw1_b1, nw1_g, nw1_be, nw1_w2, nw1_b2,
                                    nw2_w1, nw2_b1, nw2_g, nw2_be, nw2_w2, nw2_b2, out);
}